// Round 7
// baseline (500.099 us; speedup 1.0000x reference)
//
#include <hip/hip_runtime.h>
#include <hip/hip_bf16.h>

#define D_ 1024
#define B_ 4
#define S_ 4096

typedef __attribute__((ext_vector_type(8))) short bf16x8;
typedef __attribute__((ext_vector_type(4))) float f32x4;
typedef __attribute__((ext_vector_type(4))) unsigned int u32x4;
typedef __attribute__((ext_vector_type(4))) unsigned short u16x4;

__device__ __forceinline__ unsigned short f2bf(float f) {
    unsigned int u = __builtin_bit_cast(unsigned int, f);
    u = u + 0x7fffu + ((u >> 16) & 1u);
    return (unsigned short)(u >> 16);
}
__device__ __forceinline__ unsigned int pk2(float a, float b) {
    return (unsigned int)f2bf(a) | ((unsigned int)f2bf(b) << 16);
}
__device__ __forceinline__ float bf2f(unsigned short h) {
    unsigned int u = ((unsigned int)h) << 16;
    return __builtin_bit_cast(float, u);
}
__device__ __forceinline__ void gload16(const void* g, void* l) {
    __builtin_amdgcn_global_load_lds(
        (const __attribute__((address_space(1))) void*)g,
        (__attribute__((address_space(3))) void*)l, 16, 0, 0);
}

// ---------------- elementwise helpers ----------------
__global__ __launch_bounds__(256)
void conv_bf16(const float* __restrict__ src, unsigned short* __restrict__ dst, int n8) {
    int i = blockIdx.x * blockDim.x + threadIdx.x;
    const int stride = gridDim.x * blockDim.x;
    for (; i < n8; i += stride) {
        f32x4 v0 = *(const f32x4*)(src + (size_t)i * 8);
        f32x4 v1 = *(const f32x4*)(src + (size_t)i * 8 + 4);
        u32x4 o;
        o[0] = pk2(v0[0], v0[1]);
        o[1] = pk2(v0[2], v0[3]);
        o[2] = pk2(v1[0], v1[1]);
        o[3] = pk2(v1[2], v1[3]);
        *(u32x4*)(dst + (size_t)i * 8) = o;
    }
}

__global__ __launch_bounds__(256)
void conv_bf16_w4(const float* __restrict__ s0, const float* __restrict__ s1,
                  const float* __restrict__ s2, const float* __restrict__ s3,
                  unsigned short* __restrict__ d0, unsigned short* __restrict__ d1,
                  unsigned short* __restrict__ d2, unsigned short* __restrict__ d3,
                  int n8_per) {
    int i = blockIdx.x * blockDim.x + threadIdx.x;
    const int stride = gridDim.x * blockDim.x;
    for (; i < 4 * n8_per; i += stride) {
        int w = i / n8_per;
        size_t j = (size_t)(i - w * n8_per) * 8;
        const float* s = (w == 0) ? s0 : (w == 1) ? s1 : (w == 2) ? s2 : s3;
        unsigned short* d = (w == 0) ? d0 : (w == 1) ? d1 : (w == 2) ? d2 : d3;
        f32x4 v0 = *(const f32x4*)(s + j);
        f32x4 v1 = *(const f32x4*)(s + j + 4);
        u32x4 o;
        o[0] = pk2(v0[0], v0[1]);
        o[1] = pk2(v0[2], v0[3]);
        o[2] = pk2(v1[0], v1[1]);
        o[3] = pk2(v1[2], v1[3]);
        *(u32x4*)(d + j) = o;
    }
}

// E[b][i] = sum_seg P[b*split+seg][i]
__global__ __launch_bounds__(256)
void reduceN_bf16(const unsigned short* __restrict__ P, unsigned short* __restrict__ E,
                  int split, int n8_total) {
    int t = blockIdx.x * blockDim.x + threadIdx.x;
    const int stride = gridDim.x * blockDim.x;
    const int DD = D_ * D_;
    for (; t < n8_total; t += stride) {
        size_t idx = (size_t)t * 8;
        int b = (int)(idx / DD);
        size_t i = idx % DD;
        float s[8];
#pragma unroll
        for (int k = 0; k < 8; ++k) s[k] = 0.f;
        for (int seg = 0; seg < split; ++seg) {
            const unsigned short* p = P + (size_t)(b * split + seg) * DD + i;
            u16x4 v0 = *(const u16x4*)p;
            u16x4 v1 = *(const u16x4*)(p + 4);
#pragma unroll
            for (int k = 0; k < 4; ++k) { s[k] += bf2f(v0[k]); s[4 + k] += bf2f(v1[k]); }
        }
        u16x4 o0, o1;
#pragma unroll
        for (int k = 0; k < 4; ++k) { o0[k] = f2bf(s[k]); o1[k] = f2bf(s[4 + k]); }
        *(u16x4*)(E + idx) = o0;
        *(u16x4*)(E + idx + 4) = o1;
    }
}

// ---------------- 128x128 2-phase kernel (proven; small F-GEMM only) ----------------
#define BM 128
#define BN 128
#define BK 64
#define NTHR 256

template<bool OUT_F32, bool TRANS, bool RELU>
__global__ __launch_bounds__(NTHR)
void gemm_nt(const unsigned short* __restrict__ Ap, const unsigned short* __restrict__ Bp,
             void* __restrict__ Op, int M, int N, int K, int klen, int split,
             long long sA, long long sB, long long sO)
{
    __shared__ char lds_a[BM * BK * 2];
    __shared__ char lds_b[BN * BK * 2];

    const int tid   = threadIdx.x;
    const int bz    = blockIdx.z;
    const int batch = bz / split;
    const int k0    = (bz % split) * klen;
    const int bm    = blockIdx.y * BM;
    const int bn    = blockIdx.x * BN;

    const unsigned short* Abase = Ap + (size_t)batch * sA + (size_t)bm * K;
    const unsigned short* Bbase = Bp + (size_t)batch * sB + (size_t)bn * K;

    const int lane = tid & 63;
    const int wave = tid >> 6;
    const int wm   = (wave >> 1) * 64;
    const int wn   = (wave & 1) * 64;
    const int l16  = lane & 15;
    const int lhi  = lane >> 4;

    const int srow0 = wave * 32 + (lane >> 3);
    const int schnk = (lane & 7) ^ (lane >> 3);
    const char* gA0 = (const char*)(Abase + (size_t)srow0 * K) + schnk * 16;
    const char* gB0 = (const char*)(Bbase + (size_t)srow0 * K) + schnk * 16;
    char* lA0 = lds_a + wave * 4096;
    char* lB0 = lds_b + wave * 4096;

    f32x4 acc[4][4];
#pragma unroll
    for (int i = 0; i < 4; ++i)
#pragma unroll
        for (int j = 0; j < 4; ++j)
            acc[i][j] = (f32x4){0.f, 0.f, 0.f, 0.f};

    for (int kt = k0; kt < k0 + klen; kt += BK) {
#pragma unroll
        for (int p = 0; p < 4; ++p)
            gload16(gA0 + ((size_t)p * 8 * K + kt) * 2, lA0 + p * 1024);
#pragma unroll
        for (int p = 0; p < 4; ++p)
            gload16(gB0 + ((size_t)p * 8 * K + kt) * 2, lB0 + p * 1024);
        __syncthreads();
#pragma unroll
        for (int kk = 0; kk < BK / 32; ++kk) {
            bf16x8 af[4], bfr[4];
#pragma unroll
            for (int i = 0; i < 4; ++i) {
                int row = wm + i * 16 + l16;
                int byt = (row * 128 + kk * 64 + lhi * 16) ^ ((row & 7) << 4);
                af[i] = *(const bf16x8*)(lds_a + byt);
            }
#pragma unroll
            for (int j = 0; j < 4; ++j) {
                int row = wn + j * 16 + l16;
                int byt = (row * 128 + kk * 64 + lhi * 16) ^ ((row & 7) << 4);
                bfr[j] = *(const bf16x8*)(lds_b + byt);
            }
#pragma unroll
            for (int i = 0; i < 4; ++i)
#pragma unroll
                for (int j = 0; j < 4; ++j)
                    acc[i][j] = __builtin_amdgcn_mfma_f32_16x16x32_bf16(af[i], bfr[j], acc[i][j], 0, 0, 0);
        }
        __syncthreads();
    }

    const size_t obase = (size_t)bz * (size_t)sO;
    if constexpr (!TRANS) {
#pragma unroll
        for (int i = 0; i < 4; ++i) {
            const int m0 = bm + wm + i * 16 + lhi * 4;
#pragma unroll
            for (int j = 0; j < 4; ++j) {
                const int n = bn + wn + j * 16 + l16;
#pragma unroll
                for (int r = 0; r < 4; ++r) {
                    float v = acc[i][j][r];
                    if constexpr (RELU) v = fmaxf(v, 0.f);
                    size_t addr = obase + (size_t)(m0 + r) * N + n;
                    if constexpr (OUT_F32) ((float*)Op)[addr] = v;
                    else ((unsigned short*)Op)[addr] = f2bf(v);
                }
            }
        }
    } else {
#pragma unroll
        for (int i = 0; i < 4; ++i) {
            const int m0 = bm + wm + i * 16 + lhi * 4;
#pragma unroll
            for (int j = 0; j < 4; ++j) {
                const int n = bn + wn + j * 16 + l16;
                u16x4 h;
#pragma unroll
                for (int r = 0; r < 4; ++r) {
                    float v = acc[i][j][r];
                    if constexpr (RELU) v = fmaxf(v, 0.f);
                    h[r] = f2bf(v);
                }
                *(u16x4*)((unsigned short*)Op + obase + (size_t)n * M + m0) = h;
            }
        }
    }
}

// ---------------- 256x256 8-phase kernel, read-pipelined (round 7) ----------------
// Fragment ds_reads for phase p+1 issue right after phase p's first barrier
// (or pre-barrier when DMA-safety allows) and drain UNDER phase p's MFMA; the
// compiler's counted lgkm waits enforce the dependency. Restage safety: buf
// overwrites happen only at a phase start after the end-barrier of the phase
// whose MFMA consumed (compiler-waited) the last reads of that buffer.
// Collective DMA visibility: vmcnt(4)+barrier at ph4/ph8 BEFORE the reads of
// the newly staged buffer are issued. Stage slots B@ph3, A@ph4, B@ph7, A@ph8
// (4-5 phase prefetch distance).
#define CTILE 65536
#define CBOFF 32768

template<bool OUT_F32, bool TRANS, bool RELU>
__global__ __launch_bounds__(512, 2)
void gemm256(const unsigned short* __restrict__ Ap, const unsigned short* __restrict__ Bp,
             void* __restrict__ Op, int M, int N, int K, int klen, int split,
             long long sA, long long sB, long long sO)
{
    __shared__ char lds[131072];
    const int tid  = threadIdx.x;
    const int wave = tid >> 6;
    const int lane = tid & 63;

    // XCD-aware bijective block swizzle (all grids have nwg % 8 == 0)
    const int gx = gridDim.x, gy = gridDim.y;
    const int f   = blockIdx.x + gx * (blockIdx.y + gy * blockIdx.z);
    const int nwg = gx * gy * (int)gridDim.z;
    const int s   = (f & 7) * (nwg >> 3) + (f >> 3);
    const int lx  = s % gx;
    const int lyz = s / gx;
    const int ly  = lyz % gy;
    const int lz  = lyz / gy;

    const int batch = lz / split;
    const int k0    = (lz % split) * klen;
    const int bm    = ly * 256;
    const int bn    = lx * 256;

    const int wm  = (wave >> 2) * 128;
    const int wn  = (wave & 3) * 64;
    const int l16 = lane & 15, lhi = lane >> 4;

    const unsigned short* Abase = Ap + (size_t)batch * sA + (size_t)bm * K;
    const unsigned short* Bbase = Bp + (size_t)batch * sB + (size_t)bn * K;
    const int srow  = lane >> 3;
    const int schnk = (lane & 7) ^ srow;
    const size_t K2 = (size_t)K * 2;
    const char* gA = (const char*)Abase + (size_t)srow * K2 + (size_t)schnk * 16 + (size_t)k0 * 2;
    const char* gB = (const char*)Bbase + (size_t)srow * K2 + (size_t)schnk * 16 + (size_t)k0 * 2;

    f32x4 acc[8][4];
#pragma unroll
    for (int i = 0; i < 8; ++i)
#pragma unroll
        for (int j = 0; j < 4; ++j)
            acc[i][j] = (f32x4){0.f, 0.f, 0.f, 0.f};

    // double fragment sets: a1/a2 (mh halves), b0/b1 (nh halves)
    bf16x8 a1[4][2], a2[4][2], b0[2][2], b1[2][2];

    auto stageA = [&](int c, int t) {
#pragma unroll
        for (int h = 0; h < 2; ++h)
#pragma unroll
            for (int p = 0; p < 2; ++p)
                gload16(gA + (size_t)t * 128 + (size_t)(h * 128 + wave * 16 + p * 8) * K2,
                        lds + c * CTILE + h * 16384 + wave * 2048 + p * 1024);
    };
    auto stageB = [&](int c, int t) {
#pragma unroll
        for (int h = 0; h < 2; ++h)
#pragma unroll
            for (int p = 0; p < 2; ++p)
                gload16(gB + (size_t)t * 128 + (size_t)(h * 128 + wave * 16 + p * 8) * K2,
                        lds + c * CTILE + CBOFF + h * 16384 + wave * 2048 + p * 1024);
    };
    auto ldAh = [&](int c, int mh, bf16x8 (&dst)[4][2]) {
#pragma unroll
        for (int i4 = 0; i4 < 4; ++i4)
#pragma unroll
            for (int kk = 0; kk < 2; ++kk) {
                int row = wm + mh * 64 + i4 * 16 + l16;
                int byt = (row * 128 + kk * 64 + lhi * 16) ^ ((row & 7) << 4);
                dst[i4][kk] = *(const bf16x8*)(lds + c * CTILE + byt);
            }
    };
    auto ldBh = [&](int c, int nh, bf16x8 (&dst)[2][2]) {
#pragma unroll
        for (int j2 = 0; j2 < 2; ++j2)
#pragma unroll
            for (int kk = 0; kk < 2; ++kk) {
                int row = wn + nh * 32 + j2 * 16 + l16;
                int byt = (row * 128 + kk * 64 + lhi * 16) ^ ((row & 7) << 4);
                dst[j2][kk] = *(const bf16x8*)(lds + c * CTILE + CBOFF + byt);
            }
    };
    auto mm = [&](int mh, int nh, bf16x8 (&aS)[4][2], bf16x8 (&bS)[2][2]) {
        __builtin_amdgcn_s_setprio(1);
#pragma unroll
        for (int i4 = 0; i4 < 4; ++i4)
#pragma unroll
            for (int j2 = 0; j2 < 2; ++j2)
#pragma unroll
                for (int kk = 0; kk < 2; ++kk)
                    acc[mh * 4 + i4][nh * 2 + j2] = __builtin_amdgcn_mfma_f32_16x16x32_bf16(
                        aS[i4][kk], bS[j2][kk], acc[mh * 4 + i4][nh * 2 + j2], 0, 0, 0);
        __builtin_amdgcn_s_setprio(0);
    };

#define BAR()  __builtin_amdgcn_s_barrier()
#define VM4()  asm volatile("s_waitcnt vmcnt(4)" ::: "memory")
#define VM8()  asm volatile("s_waitcnt vmcnt(8)" ::: "memory")

    const int NT  = klen / 64;
    const int NI  = NT / 2;
    // prologue: both tiles staged; collective cert of buf0 via vmcnt(8)+bar
    stageA(0, 0); stageB(0, 0); stageA(1, 1); stageB(1, 1);
    VM8();
    BAR();
    ldAh(0, 0, a1); ldBh(0, 0, b0);   // R1: fragments for ph1

    for (int itr = 0; itr < NI; ++itr) {
        const int tp0 = (2 * itr + 2) % NT;
        const int tp1 = (2 * itr + 3) % NT;
        // ph1: prefetch R2 (b1), compute (0,0)
        ldBh(0, 1, b1);
        BAR(); mm(0, 0, a1, b0); BAR();
        // ph2: prefetch R3 (a2), compute (0,1)
        ldAh(0, 1, a2);
        BAR(); mm(0, 1, a1, b1); BAR();
        // ph3: buf0-B fully consumed (reads drained before bar2(ph2)) -> restage
        stageB(0, tp0);
        BAR(); mm(1, 0, a2, b0); BAR();
        // ph4: buf0-A consumed -> restage; vmcnt(4)+bar certifies buf1 DMA
        //      (all waves) BEFORE issuing buf1 reads R5
        VM4(); stageA(0, tp0);
        BAR();
        ldAh(1, 0, a1); ldBh(1, 0, b0);   // R5, drains under mm
        mm(1, 1, a2, b1);
        BAR();
        // ph5
        ldBh(1, 1, b1);
        BAR(); mm(0, 0, a1, b0); BAR();
        // ph6
        ldAh(1, 1, a2);
        BAR(); mm(0, 1, a1, b1); BAR();
        // ph7
        stageB(1, tp1);
        BAR(); mm(1, 0, a2, b0); BAR();
        // ph8
        VM4(); stageA(1, tp1);
        BAR();
        if (itr + 1 < NI) { ldAh(0, 0, a1); ldBh(0, 0, b0); }   // R1''
        mm(1, 1, a2, b1);
        BAR();
    }
    asm volatile("s_waitcnt vmcnt(0)" ::: "memory");

    const size_t obase = (size_t)lz * (size_t)sO;
    if constexpr (!TRANS) {
#pragma unroll
        for (int i = 0; i < 8; ++i) {
            const int m0 = bm + wm + i * 16 + lhi * 4;
#pragma unroll
            for (int j = 0; j < 4; ++j) {
                const int n = bn + wn + j * 16 + l16;
#pragma unroll
                for (int r = 0; r < 4; ++r) {
                    float v = acc[i][j][r];
                    if constexpr (RELU) v = fmaxf(v, 0.f);
                    size_t addr = obase + (size_t)(m0 + r) * N + n;
                    if constexpr (OUT_F32) ((float*)Op)[addr] = v;
                    else ((unsigned short*)Op)[addr] = f2bf(v);
                }
            }
        }
    } else {
#pragma unroll
        for (int i = 0; i < 8; ++i) {
            const int m0 = bm + wm + i * 16 + lhi * 4;
#pragma unroll
            for (int j = 0; j < 4; ++j) {
                const int n = bn + wn + j * 16 + l16;
                u16x4 h;
#pragma unroll
                for (int r = 0; r < 4; ++r) {
                    float v = acc[i][j][r];
                    if constexpr (RELU) v = fmaxf(v, 0.f);
                    h[r] = f2bf(v);
                }
                *(u16x4*)((unsigned short*)Op + obase + (size_t)n * M + m0) = h;
            }
        }
    }
#undef BAR
#undef VM4
#undef VM8
}

extern "C" void kernel_launch(void* const* d_in, const int* in_sizes, int n_in,
                              void* d_out, int out_size, void* d_ws, size_t ws_size,
                              hipStream_t stream) {
    (void)in_sizes; (void)n_in; (void)out_size;
    const float* x  = (const float*)d_in[0];
    const float* Wa = (const float*)d_in[1];
    const float* Wb = (const float*)d_in[2];
    const float* Wc = (const float*)d_in[3];
    const float* Wd = (const float*)d_in[4];

    const long long SD  = (long long)S_ * D_;
    const long long DD2 = (long long)D_ * D_;
    const size_t MB = 1024 * 1024;

    unsigned short* r0 = (unsigned short*)d_ws;
    unsigned short* r1 = (unsigned short*)((char*)d_ws + 32 * MB);
    unsigned short* Ft = r1;
    const bool big_ws = ws_size >= (size_t)96 * MB;

    char* ob = (char*)d_out;
    unsigned short* xb    = (unsigned short*)ob;
    unsigned short* Pp    = big_ws ? (unsigned short*)((char*)d_ws + 64 * MB)
                                   : (unsigned short*)(ob + 32 * MB);
    unsigned short* Enorm = (unsigned short*)(ob + 48 * MB);
    unsigned short* Wbb   = (unsigned short*)(ob + 56 * MB);
    unsigned short* Wcb   = (unsigned short*)(ob + 58 * MB);
    unsigned short* Wab   = (unsigned short*)(ob + 60 * MB);
    unsigned short* Wdb   = (unsigned short*)(ob + 62 * MB);
    const int esplit = big_ws ? 4 : 2;
    const int eklen  = S_ / esplit;

    dim3 blk256(256, 1, 1);
    dim3 blk512(512, 1, 1);
    dim3 gS(D_ / 256, S_ / 256, B_);          // (4,16,4) = 256 blocks
    dim3 gE(D_ / 256, D_ / 256, B_ * esplit); // (4,4,16) or (4,4,8)
    dim3 gF(D_ / BN, D_ / BM, B_);            // (8,8,4)

    // 0) bf16-ify inputs (weights in ONE launch)
    conv_bf16<<<2048, blk256, 0, stream>>>(x, xb, (B_ * S_ * D_) / 8);
    conv_bf16_w4<<<1024, blk256, 0, stream>>>(Wb, Wc, Wa, Wd, Wbb, Wcb, Wab, Wdb, (D_ * D_) / 8);

    // 1) Bmt[b][e][s] = relu(xb Wb^T)^T  -> r0
    gemm256<false, true,  true ><<<gS, blk512, 0, stream>>>(xb, Wbb, r0, S_, D_, D_, D_, 1, SD, 0, SD);
    // 2) Ct[b][e][s]  = relu(xb Wc^T)^T  -> r1
    gemm256<false, true,  true ><<<gS, blk512, 0, stream>>>(xb, Wcb, r1, S_, D_, D_, D_, 1, SD, 0, SD);
    // 3) E2 partials
    gemm256<false, false, false><<<gE, blk512, 0, stream>>>(r0, r1, Pp, D_, D_, S_, eklen, esplit, SD, SD, DD2);
    // 3b) Enorm[b] = sum_seg P
    reduceN_bf16<<<2048, blk256, 0, stream>>>(Pp, Enorm, esplit, (B_ * D_ * D_) / 8);
    // 3c) Ft = (E2 @ Wd^T)^T -> r1 (Ct dead)
    gemm_nt<false, true,  false><<<gF, blk256, 0, stream>>>(Enorm, Wdb, Ft, D_, D_, D_, D_, 1, DD2, 0, DD2);
    // 4) A = relu(xb Wa^T) -> r0 (Bmt dead)
    gemm256<false, false, true ><<<gS, blk512, 0, stream>>>(xb, Wab, r0, S_, D_, D_, D_, 1, SD, 0, SD);
    // 5) out = relu(A @ Ft-rows) f32 -> d_out
    gemm256<true,  false, true ><<<gS, blk512, 0, stream>>>(r0, Ft, (float*)d_out, S_, D_, D_, D_, 1, SD, DD2, SD);
}

// Round 8
// 253.632 us; speedup vs baseline: 1.9718x; 1.9718x over previous
//
#include <hip/hip_runtime.h>
#include <hip/hip_bf16.h>

#define D_ 1024
#define B_ 4
#define S_ 4096

typedef __attribute__((ext_vector_type(8))) short bf16x8;
typedef __attribute__((ext_vector_type(4))) float f32x4;
typedef __attribute__((ext_vector_type(4))) unsigned int u32x4;
typedef __attribute__((ext_vector_type(4))) unsigned short u16x4;

__device__ __forceinline__ unsigned short f2bf(float f) {
    unsigned int u = __builtin_bit_cast(unsigned int, f);
    u = u + 0x7fffu + ((u >> 16) & 1u);
    return (unsigned short)(u >> 16);
}
__device__ __forceinline__ unsigned int pk2(float a, float b) {
    return (unsigned int)f2bf(a) | ((unsigned int)f2bf(b) << 16);
}
__device__ __forceinline__ float bf2f(unsigned short h) {
    unsigned int u = ((unsigned int)h) << 16;
    return __builtin_bit_cast(float, u);
}
__device__ __forceinline__ void gload16(const void* g, void* l) {
    __builtin_amdgcn_global_load_lds(
        (const __attribute__((address_space(1))) void*)g,
        (__attribute__((address_space(3))) void*)l, 16, 0, 0);
}

// ---------------- elementwise helpers ----------------
__global__ __launch_bounds__(256)
void conv_bf16(const float* __restrict__ src, unsigned short* __restrict__ dst, int n8) {
    int i = blockIdx.x * blockDim.x + threadIdx.x;
    const int stride = gridDim.x * blockDim.x;
    for (; i < n8; i += stride) {
        f32x4 v0 = *(const f32x4*)(src + (size_t)i * 8);
        f32x4 v1 = *(const f32x4*)(src + (size_t)i * 8 + 4);
        u32x4 o;
        o[0] = pk2(v0[0], v0[1]);
        o[1] = pk2(v0[2], v0[3]);
        o[2] = pk2(v1[0], v1[1]);
        o[3] = pk2(v1[2], v1[3]);
        *(u32x4*)(dst + (size_t)i * 8) = o;
    }
}

__global__ __launch_bounds__(256)
void conv_bf16_w2(const float* __restrict__ s0, const float* __restrict__ s1,
                  unsigned short* __restrict__ d0, unsigned short* __restrict__ d1,
                  int n8_per) {
    int i = blockIdx.x * blockDim.x + threadIdx.x;
    const int stride = gridDim.x * blockDim.x;
    for (; i < 2 * n8_per; i += stride) {
        int w = i / n8_per;
        size_t j = (size_t)(i - w * n8_per) * 8;
        const float* s = w ? s1 : s0;
        unsigned short* d = w ? d1 : d0;
        f32x4 v0 = *(const f32x4*)(s + j);
        f32x4 v1 = *(const f32x4*)(s + j + 4);
        u32x4 o;
        o[0] = pk2(v0[0], v0[1]);
        o[1] = pk2(v0[2], v0[3]);
        o[2] = pk2(v1[0], v1[1]);
        o[3] = pk2(v1[2], v1[3]);
        *(u32x4*)(d + j) = o;
    }
}

// In-place segment reduce: E[b][i] = sum_seg P[b*split+seg][i], E stored at P[b*split].
__global__ __launch_bounds__(256)
void reduceN_bf16_inplace(unsigned short* __restrict__ P, int split, int n8_total) {
    int t = blockIdx.x * blockDim.x + threadIdx.x;
    const int stride = gridDim.x * blockDim.x;
    const int DD = D_ * D_;
    for (; t < n8_total; t += stride) {
        size_t idx = (size_t)t * 8;
        int b = (int)(idx / DD);
        size_t i = idx % DD;
        float s[8];
#pragma unroll
        for (int k = 0; k < 8; ++k) s[k] = 0.f;
        for (int seg = 0; seg < split; ++seg) {
            const unsigned short* p = P + (size_t)(b * split + seg) * DD + i;
            u16x4 v0 = *(const u16x4*)p;
            u16x4 v1 = *(const u16x4*)(p + 4);
#pragma unroll
            for (int k = 0; k < 4; ++k) { s[k] += bf2f(v0[k]); s[4 + k] += bf2f(v1[k]); }
        }
        u16x4 o0, o1;
#pragma unroll
        for (int k = 0; k < 4; ++k) { o0[k] = f2bf(s[k]); o1[k] = f2bf(s[4 + k]); }
        unsigned short* e = P + (size_t)(b * split) * DD + i;
        *(u16x4*)e = o0;
        *(u16x4*)(e + 4) = o1;
    }
}

// ---------------- 128x128 2-phase kernel (proven; small F-GEMM only) ----------------
#define BM 128
#define BN 128
#define BK 64
#define NTHR 256

template<bool OUT_F32, bool TRANS, bool RELU>
__global__ __launch_bounds__(NTHR)
void gemm_nt(const unsigned short* __restrict__ Ap, const unsigned short* __restrict__ Bp,
             void* __restrict__ Op, int M, int N, int K, int klen, int split,
             long long sA, long long sB, long long sO)
{
    __shared__ char lds_a[BM * BK * 2];
    __shared__ char lds_b[BN * BK * 2];

    const int tid   = threadIdx.x;
    const int bz    = blockIdx.z;
    const int batch = bz / split;
    const int k0    = (bz % split) * klen;
    const int bm    = blockIdx.y * BM;
    const int bn    = blockIdx.x * BN;

    const unsigned short* Abase = Ap + (size_t)batch * sA + (size_t)bm * K;
    const unsigned short* Bbase = Bp + (size_t)batch * sB + (size_t)bn * K;

    const int lane = tid & 63;
    const int wave = tid >> 6;
    const int wm   = (wave >> 1) * 64;
    const int wn   = (wave & 1) * 64;
    const int l16  = lane & 15;
    const int lhi  = lane >> 4;

    const int srow0 = wave * 32 + (lane >> 3);
    const int schnk = (lane & 7) ^ (lane >> 3);
    const char* gA0 = (const char*)(Abase + (size_t)srow0 * K) + schnk * 16;
    const char* gB0 = (const char*)(Bbase + (size_t)srow0 * K) + schnk * 16;
    char* lA0 = lds_a + wave * 4096;
    char* lB0 = lds_b + wave * 4096;

    f32x4 acc[4][4];
#pragma unroll
    for (int i = 0; i < 4; ++i)
#pragma unroll
        for (int j = 0; j < 4; ++j)
            acc[i][j] = (f32x4){0.f, 0.f, 0.f, 0.f};

    for (int kt = k0; kt < k0 + klen; kt += BK) {
#pragma unroll
        for (int p = 0; p < 4; ++p)
            gload16(gA0 + ((size_t)p * 8 * K + kt) * 2, lA0 + p * 1024);
#pragma unroll
        for (int p = 0; p < 4; ++p)
            gload16(gB0 + ((size_t)p * 8 * K + kt) * 2, lB0 + p * 1024);
        __syncthreads();
#pragma unroll
        for (int kk = 0; kk < BK / 32; ++kk) {
            bf16x8 af[4], bfr[4];
#pragma unroll
            for (int i = 0; i < 4; ++i) {
                int row = wm + i * 16 + l16;
                int byt = (row * 128 + kk * 64 + lhi * 16) ^ ((row & 7) << 4);
                af[i] = *(const bf16x8*)(lds_a + byt);
            }
#pragma unroll
            for (int j = 0; j < 4; ++j) {
                int row = wn + j * 16 + l16;
                int byt = (row * 128 + kk * 64 + lhi * 16) ^ ((row & 7) << 4);
                bfr[j] = *(const bf16x8*)(lds_b + byt);
            }
#pragma unroll
            for (int i = 0; i < 4; ++i)
#pragma unroll
                for (int j = 0; j < 4; ++j)
                    acc[i][j] = __builtin_amdgcn_mfma_f32_16x16x32_bf16(af[i], bfr[j], acc[i][j], 0, 0, 0);
        }
        __syncthreads();
    }

    const size_t obase = (size_t)bz * (size_t)sO;
    if constexpr (!TRANS) {
#pragma unroll
        for (int i = 0; i < 4; ++i) {
            const int m0 = bm + wm + i * 16 + lhi * 4;
#pragma unroll
            for (int j = 0; j < 4; ++j) {
                const int n = bn + wn + j * 16 + l16;
#pragma unroll
                for (int r = 0; r < 4; ++r) {
                    float v = acc[i][j][r];
                    if constexpr (RELU) v = fmaxf(v, 0.f);
                    size_t addr = obase + (size_t)(m0 + r) * N + n;
                    if constexpr (OUT_F32) ((float*)Op)[addr] = v;
                    else ((unsigned short*)Op)[addr] = f2bf(v);
                }
            }
        }
    } else {
#pragma unroll
        for (int i = 0; i < 4; ++i) {
            const int m0 = bm + wm + i * 16 + lhi * 4;
#pragma unroll
            for (int j = 0; j < 4; ++j) {
                const int n = bn + wn + j * 16 + l16;
                u16x4 h;
#pragma unroll
                for (int r = 0; r < 4; ++r) {
                    float v = acc[i][j][r];
                    if constexpr (RELU) v = fmaxf(v, 0.f);
                    h[r] = f2bf(v);
                }
                *(u16x4*)((unsigned short*)Op + obase + (size_t)n * M + m0) = h;
            }
        }
    }
}

// ---------------- 256x256 8-phase kernel (r5 skeleton + fine-grained slots) ----------------
// Per phase: [ds_reads][2-load stage slot(s)] BAR lgkm0 MFMA(16) BAR.
// Single a-set + held b0/b1 (r5 register budget: 64 frag VGPR + 128 acc AGPR).
// Slot map (2 loads each), region-free per r5 proof (buf0-B free ph3, buf0-A ph4,
// buf1-B ph7, buf1-A ph8):
//   ph1: B1(t1)[0] + A1(t1)[1]   ph2: B1(t1)[1]
//   ph3: B0(t0+2)[0]             ph4: B0(t0+2)[1]; vmcnt(4) certifies buf1-t1
//   ph5: A0(t0+2)[0]             ph6: A0(t0+2)[1]
//   ph7: -                       ph8: A1(t1+2)[0]; vmcnt(2) certifies buf0-t0+2
//   (A1[1] slot wraps to next iteration's ph1)
// lgkmcnt(8) throttle before BAR on 12-read phases (ph1, ph5).
#define CTILE 65536
#define CBOFF 32768

template<bool OUT_F32, bool TRANS, bool RELU>
__global__ __launch_bounds__(512, 2)
void gemm256(const unsigned short* __restrict__ Ap, const unsigned short* __restrict__ Bp,
             void* __restrict__ Op, int M, int N, int K, int klen, int split,
             long long sA, long long sB, long long sO)
{
    __shared__ char lds[131072];
    const int tid  = threadIdx.x;
    const int wave = tid >> 6;
    const int lane = tid & 63;

    // XCD-aware bijective block swizzle (all grids have nwg % 8 == 0)
    const int gx = gridDim.x, gy = gridDim.y;
    const int f   = blockIdx.x + gx * (blockIdx.y + gy * blockIdx.z);
    const int nwg = gx * gy * (int)gridDim.z;
    const int s   = (f & 7) * (nwg >> 3) + (f >> 3);
    const int lx  = s % gx;
    const int lyz = s / gx;
    const int ly  = lyz % gy;
    const int lz  = lyz / gy;

    const int batch = lz / split;
    const int k0    = (lz % split) * klen;
    const int bm    = ly * 256;
    const int bn    = lx * 256;

    const int wm  = (wave >> 2) * 128;
    const int wn  = (wave & 3) * 64;
    const int l16 = lane & 15, lhi = lane >> 4;

    const unsigned short* Abase = Ap + (size_t)batch * sA + (size_t)bm * K;
    const unsigned short* Bbase = Bp + (size_t)batch * sB + (size_t)bn * K;
    const int srow  = lane >> 3;
    const int schnk = (lane & 7) ^ srow;
    const size_t K2 = (size_t)K * 2;
    const char* gA = (const char*)Abase + (size_t)srow * K2 + (size_t)schnk * 16 + (size_t)k0 * 2;
    const char* gB = (const char*)Bbase + (size_t)srow * K2 + (size_t)schnk * 16 + (size_t)k0 * 2;

    f32x4 acc[8][4];
#pragma unroll
    for (int i = 0; i < 8; ++i)
#pragma unroll
        for (int j = 0; j < 4; ++j)
            acc[i][j] = (f32x4){0.f, 0.f, 0.f, 0.f};

    bf16x8 a[4][2], b0[2][2], b1[2][2];

    // 2-load stage slots: h = half index (0: rows 0-127, 1: rows 128-255)
    auto stageA2 = [&](int c, int t, int h) {
#pragma unroll
        for (int p = 0; p < 2; ++p)
            gload16(gA + (size_t)t * 128 + (size_t)(h * 128 + wave * 16 + p * 8) * K2,
                    lds + c * CTILE + h * 16384 + wave * 2048 + p * 1024);
    };
    auto stageB2 = [&](int c, int t, int h) {
#pragma unroll
        for (int p = 0; p < 2; ++p)
            gload16(gB + (size_t)t * 128 + (size_t)(h * 128 + wave * 16 + p * 8) * K2,
                    lds + c * CTILE + CBOFF + h * 16384 + wave * 2048 + p * 1024);
    };
    auto ldA = [&](int c, int mh) {
#pragma unroll
        for (int i4 = 0; i4 < 4; ++i4)
#pragma unroll
            for (int kk = 0; kk < 2; ++kk) {
                int row = wm + mh * 64 + i4 * 16 + l16;
                int byt = (row * 128 + kk * 64 + lhi * 16) ^ ((row & 7) << 4);
                a[i4][kk] = *(const bf16x8*)(lds + c * CTILE + byt);
            }
    };
    auto ldB = [&](int c, int nh, bf16x8 (&bb)[2][2]) {
#pragma unroll
        for (int j2 = 0; j2 < 2; ++j2)
#pragma unroll
            for (int kk = 0; kk < 2; ++kk) {
                int row = wn + nh * 32 + j2 * 16 + l16;
                int byt = (row * 128 + kk * 64 + lhi * 16) ^ ((row & 7) << 4);
                bb[j2][kk] = *(const bf16x8*)(lds + c * CTILE + CBOFF + byt);
            }
    };
    auto mm = [&](int mh, int nh, bf16x8 (&bb)[2][2]) {
        __builtin_amdgcn_s_setprio(1);
#pragma unroll
        for (int i4 = 0; i4 < 4; ++i4)
#pragma unroll
            for (int j2 = 0; j2 < 2; ++j2)
#pragma unroll
                for (int kk = 0; kk < 2; ++kk)
                    acc[mh * 4 + i4][nh * 2 + j2] = __builtin_amdgcn_mfma_f32_16x16x32_bf16(
                        a[i4][kk], bb[j2][kk], acc[mh * 4 + i4][nh * 2 + j2], 0, 0, 0);
        __builtin_amdgcn_s_setprio(0);
    };

#define BAR()   __builtin_amdgcn_s_barrier()
#define LGKM0() asm volatile("s_waitcnt lgkmcnt(0)" ::: "memory")
#define LGKM8() asm volatile("s_waitcnt lgkmcnt(8)" ::: "memory")
#define VM4()   asm volatile("s_waitcnt vmcnt(4)" ::: "memory")
#define VM2()   asm volatile("s_waitcnt vmcnt(2)" ::: "memory")

    const int NT = klen / 64;
    // prologue: full buf0 tile 0, A-half0 of buf1 tile 1 (slot [0]); [1] staged at ph1
    stageA2(0, 0, 0); stageA2(0, 0, 1);
    stageB2(0, 0, 0); stageB2(0, 0, 1);
    stageA2(1, 1, 0);
    VM2();             // certify buf0 (first 8), keep A1[0] in flight
    BAR();

    for (int itr = 0; itr < NT / 2; ++itr) {
        const int t1  = 2 * itr + 1;
        const int tp0 = (2 * itr + 2) % NT;
        const int tp1 = (2 * itr + 3) % NT;
        // ph1: 12 reads + slots B1(t1)[0], A1(t1)[1]
        ldA(0, 0); ldB(0, 0, b0);
        stageB2(1, t1, 0); stageA2(1, t1, 1);
        LGKM8();
        BAR(); LGKM0(); mm(0, 0, b0); BAR();
        // ph2: slot B1(t1)[1]
        ldB(0, 1, b1);
        stageB2(1, t1, 1);
        BAR(); LGKM0(); mm(0, 1, b1); BAR();
        // ph3: slot B0(tp0)[0]  (buf0-B free: last read ph2)
        ldA(0, 1);
        stageB2(0, tp0, 0);
        BAR(); LGKM0(); mm(1, 0, b0); BAR();
        // ph4: slot B0(tp0)[1]; vmcnt(4) certifies buf1-t1 (A[0],A[1],B[0],B[1])
        stageB2(0, tp0, 1);
        BAR(); mm(1, 1, b1); VM4(); BAR();
        // ph5: 12 reads + slot A0(tp0)[0]  (buf0-A free: last read ph3)
        ldA(1, 0); ldB(1, 0, b0);
        stageA2(0, tp0, 0);
        LGKM8();
        BAR(); LGKM0(); mm(0, 0, b0); BAR();
        // ph6: slot A0(tp0)[1]
        ldB(1, 1, b1);
        stageA2(0, tp0, 1);
        BAR(); LGKM0(); mm(0, 1, b1); BAR();
        // ph7: no stage
        ldA(1, 1);
        BAR(); LGKM0(); mm(1, 0, b0); BAR();
        // ph8: slot A1(tp1)[0]; vmcnt(2) certifies buf0-tp0 (B ph3-4, A ph5-6)
        stageA2(1, tp1, 0);
        BAR(); mm(1, 1, b1); VM2(); BAR();
    }
    asm volatile("s_waitcnt vmcnt(0)" ::: "memory");

    const size_t obase = (size_t)lz * (size_t)sO;
    if constexpr (!TRANS) {
#pragma unroll
        for (int i = 0; i < 8; ++i) {
            const int m0 = bm + wm + i * 16 + lhi * 4;
#pragma unroll
            for (int j = 0; j < 4; ++j) {
                const int n = bn + wn + j * 16 + l16;
#pragma unroll
                for (int r = 0; r < 4; ++r) {
                    float v = acc[i][j][r];
                    if constexpr (RELU) v = fmaxf(v, 0.f);
                    size_t addr = obase + (size_t)(m0 + r) * N + n;
                    if constexpr (OUT_F32) ((float*)Op)[addr] = v;
                    else ((unsigned short*)Op)[addr] = f2bf(v);
                }
            }
        }
    } else {
#pragma unroll
        for (int i = 0; i < 8; ++i) {
            const int m0 = bm + wm + i * 16 + lhi * 4;
#pragma unroll
            for (int j = 0; j < 4; ++j) {
                const int n = bn + wn + j * 16 + l16;
                u16x4 h;
#pragma unroll
                for (int r = 0; r < 4; ++r) {
                    float v = acc[i][j][r];
                    if constexpr (RELU) v = fmaxf(v, 0.f);
                    h[r] = f2bf(v);
                }
                *(u16x4*)((unsigned short*)Op + obase + (size_t)n * M + m0) = h;
            }
        }
    }
#undef BAR
#undef LGKM0
#undef LGKM8
#undef VM4
#undef VM2
}

extern "C" void kernel_launch(void* const* d_in, const int* in_sizes, int n_in,
                              void* d_out, int out_size, void* d_ws, size_t ws_size,
                              hipStream_t stream) {
    (void)in_sizes; (void)n_in; (void)out_size; (void)ws_size;
    const float* x  = (const float*)d_in[0];
    const float* Wa = (const float*)d_in[1];
    const float* Wb = (const float*)d_in[2];
    const float* Wc = (const float*)d_in[3];
    const float* Wd = (const float*)d_in[4];

    const long long SD  = (long long)S_ * D_;
    const long long DD2 = (long long)D_ * D_;
    const size_t MB = 1024 * 1024;

    // ws (64MB): fused BC output [b][2048][S] bf16 = 64MB exactly.
    //   After E: BC dead -> A @0-32MB, Ft @32-40MB.
    unsigned short* BC = (unsigned short*)d_ws;
    unsigned short* Ao = (unsigned short*)d_ws;
    unsigned short* Ft = (unsigned short*)((char*)d_ws + 32 * MB);
    // d_out scratch (64MB): xb@0-32 | P (16 segs x 2MB) @32-64.
    //   Wbb@56,Wcb@58 die after projBC (overwritten by P segs 12-15).
    //   After reduce: Enorm[b] in-place at P[4b]; dead segs 1-2 -> Wdb@34, Wab@36.
    char* ob = (char*)d_out;
    unsigned short* xb    = (unsigned short*)ob;
    unsigned short* Pp    = (unsigned short*)(ob + 32 * MB);
    unsigned short* Enorm = Pp;                              // batch stride 4*DD2
    unsigned short* Wdb   = (unsigned short*)(ob + 34 * MB);
    unsigned short* Wab   = (unsigned short*)(ob + 36 * MB);
    unsigned short* Wbb   = (unsigned short*)(ob + 56 * MB); // Wbb|Wcb contiguous
    unsigned short* Wcb   = (unsigned short*)(ob + 58 * MB);

    dim3 blk256(256, 1, 1);
    dim3 blk512(512, 1, 1);
    dim3 gBC(2048 / 256, S_ / 256, B_);        // (8,16,4) = 512
    dim3 gE(D_ / 256, D_ / 256, B_ * 4);       // (4,4,16) = 256, split-K=4
    dim3 gS(D_ / 256, S_ / 256, B_);           // (4,16,4) = 256
    dim3 gF(D_ / BN, D_ / BM, B_);             // (8,8,4)

    // 0) convert x and Wb|Wc
    conv_bf16<<<2048, blk256, 0, stream>>>(x, xb, (B_ * S_ * D_) / 8);
    conv_bf16_w2<<<512, blk256, 0, stream>>>(Wb, Wc, Wbb, Wcb, (D_ * D_) / 8);
    // 1) fused projections: BC[b][n][s] = relu(xb [Wb;Wc]^T)^T, n in [0,2048)
    gemm256<false, true,  true ><<<gBC, blk512, 0, stream>>>(xb, Wbb, BC, S_, 2048, D_, D_, 1, SD, 0, 2 * SD);
    // 2) E partials: P[b*4+seg] = sum_{s in seg} Bm[s,e] C[s,e']
    gemm256<false, false, false><<<gE, blk512, 0, stream>>>(BC, BC + SD, Pp, D_, D_, S_, S_ / 4, 4, 2 * SD, 2 * SD, DD2);
    // 2b) Enorm[b] = sum_seg P  (in-place at P[4b])
    reduceN_bf16_inplace<<<2048, blk256, 0, stream>>>(Pp, 4, (B_ * D_ * D_) / 8);
    // 2c) convert Wd, Wa into dead P segs 1-2
    conv_bf16_w2<<<512, blk256, 0, stream>>>(Wd, Wa, Wdb, Wab, (D_ * D_) / 8);
    // 3) Ft[b][dout][e] = (Enorm[b] @ Wd^T)^T
    gemm_nt<false, true,  false><<<gF, blk256, 0, stream>>>(Enorm, Wdb, Ft, D_, D_, D_, D_, 1, 4 * DD2, 0, DD2);
    // 4) A[b][s][e] = relu(xb Wa^T) -> ws@0 (BC dead)
    gemm256<false, false, true ><<<gS, blk512, 0, stream>>>(xb, Wab, Ao, S_, D_, D_, D_, 1, SD, 0, SD);
    // 5) out = relu(A @ Ft-rows) f32 -> d_out (reads only ws; overwrites d_out)
    gemm256<true,  false, true ><<<gS, blk512, 0, stream>>>(Ao, Ft, (float*)d_out, S_, D_, D_, D_, 1, SD, DD2, SD);
}

// Round 10
// 243.396 us; speedup vs baseline: 2.0547x; 1.0421x over previous
//
#include <hip/hip_runtime.h>
#include <hip/hip_bf16.h>

#define D_ 1024
#define B_ 4
#define S_ 4096

typedef __attribute__((ext_vector_type(8))) short bf16x8;
typedef __attribute__((ext_vector_type(4))) float f32x4;
typedef __attribute__((ext_vector_type(4))) unsigned int u32x4;
typedef __attribute__((ext_vector_type(4))) unsigned short u16x4;

__device__ __forceinline__ unsigned short f2bf(float f) {
    unsigned int u = __builtin_bit_cast(unsigned int, f);
    u = u + 0x7fffu + ((u >> 16) & 1u);
    return (unsigned short)(u >> 16);
}
__device__ __forceinline__ unsigned int pk2(float a, float b) {
    return (unsigned int)f2bf(a) | ((unsigned int)f2bf(b) << 16);
}
__device__ __forceinline__ float bf2f(unsigned short h) {
    unsigned int u = ((unsigned int)h) << 16;
    return __builtin_bit_cast(float, u);
}
__device__ __forceinline__ void gload16(const void* g, void* l) {
    __builtin_amdgcn_global_load_lds(
        (const __attribute__((address_space(1))) void*)g,
        (__attribute__((address_space(3))) void*)l, 16, 0, 0);
}

// ---------------- elementwise helpers ----------------
__global__ __launch_bounds__(256)
void conv_bf16(const float* __restrict__ src, unsigned short* __restrict__ dst, int n8) {
    int i = blockIdx.x * blockDim.x + threadIdx.x;
    const int stride = gridDim.x * blockDim.x;
    for (; i < n8; i += stride) {
        f32x4 v0 = *(const f32x4*)(src + (size_t)i * 8);
        f32x4 v1 = *(const f32x4*)(src + (size_t)i * 8 + 4);
        u32x4 o;
        o[0] = pk2(v0[0], v0[1]);
        o[1] = pk2(v0[2], v0[3]);
        o[2] = pk2(v1[0], v1[1]);
        o[3] = pk2(v1[2], v1[3]);
        *(u32x4*)(dst + (size_t)i * 8) = o;
    }
}

__global__ __launch_bounds__(256)
void conv_bf16_w2(const float* __restrict__ s0, const float* __restrict__ s1,
                  unsigned short* __restrict__ d0, unsigned short* __restrict__ d1,
                  int n8_per) {
    int i = blockIdx.x * blockDim.x + threadIdx.x;
    const int stride = gridDim.x * blockDim.x;
    for (; i < 2 * n8_per; i += stride) {
        int w = i / n8_per;
        size_t j = (size_t)(i - w * n8_per) * 8;
        const float* s = w ? s1 : s0;
        unsigned short* d = w ? d1 : d0;
        f32x4 v0 = *(const f32x4*)(s + j);
        f32x4 v1 = *(const f32x4*)(s + j + 4);
        u32x4 o;
        o[0] = pk2(v0[0], v0[1]);
        o[1] = pk2(v0[2], v0[3]);
        o[2] = pk2(v1[0], v1[1]);
        o[3] = pk2(v1[2], v1[3]);
        *(u32x4*)(d + j) = o;
    }
}

// In-place segment reduce: E[b][i] = sum_seg P[b*split+seg][i], E stored at P[b*split].
__global__ __launch_bounds__(256)
void reduceN_bf16_inplace(unsigned short* __restrict__ P, int split, int n8_total) {
    int t = blockIdx.x * blockDim.x + threadIdx.x;
    const int stride = gridDim.x * blockDim.x;
    const int DD = D_ * D_;
    for (; t < n8_total; t += stride) {
        size_t idx = (size_t)t * 8;
        int b = (int)(idx / DD);
        size_t i = idx % DD;
        float s[8];
#pragma unroll
        for (int k = 0; k < 8; ++k) s[k] = 0.f;
        for (int seg = 0; seg < split; ++seg) {
            const unsigned short* p = P + (size_t)(b * split + seg) * DD + i;
            u16x4 v0 = *(const u16x4*)p;
            u16x4 v1 = *(const u16x4*)(p + 4);
#pragma unroll
            for (int k = 0; k < 4; ++k) { s[k] += bf2f(v0[k]); s[4 + k] += bf2f(v1[k]); }
        }
        u16x4 o0, o1;
#pragma unroll
        for (int k = 0; k < 4; ++k) { o0[k] = f2bf(s[k]); o1[k] = f2bf(s[4 + k]); }
        unsigned short* e = P + (size_t)(b * split) * DD + i;
        *(u16x4*)e = o0;
        *(u16x4*)(e + 4) = o1;
    }
}

// ---------------- 128x128 2-phase kernel (proven; small F-GEMM only) ----------------
#define BM 128
#define BN 128
#define BK 64
#define NTHR 256

template<bool OUT_F32, bool TRANS, bool RELU>
__global__ __launch_bounds__(NTHR)
void gemm_nt(const unsigned short* __restrict__ Ap, const unsigned short* __restrict__ Bp,
             void* __restrict__ Op, int M, int N, int K, int klen, int split,
             long long sA, long long sB, long long sO)
{
    __shared__ char lds_a[BM * BK * 2];
    __shared__ char lds_b[BN * BK * 2];

    const int tid   = threadIdx.x;
    const int bz    = blockIdx.z;
    const int batch = bz / split;
    const int k0    = (bz % split) * klen;
    const int bm    = blockIdx.y * BM;
    const int bn    = blockIdx.x * BN;

    const unsigned short* Abase = Ap + (size_t)batch * sA + (size_t)bm * K;
    const unsigned short* Bbase = Bp + (size_t)batch * sB + (size_t)bn * K;

    const int lane = tid & 63;
    const int wave = tid >> 6;
    const int wm   = (wave >> 1) * 64;
    const int wn   = (wave & 1) * 64;
    const int l16  = lane & 15;
    const int lhi  = lane >> 4;

    const int srow0 = wave * 32 + (lane >> 3);
    const int schnk = (lane & 7) ^ (lane >> 3);
    const char* gA0 = (const char*)(Abase + (size_t)srow0 * K) + schnk * 16;
    const char* gB0 = (const char*)(Bbase + (size_t)srow0 * K) + schnk * 16;
    char* lA0 = lds_a + wave * 4096;
    char* lB0 = lds_b + wave * 4096;

    f32x4 acc[4][4];
#pragma unroll
    for (int i = 0; i < 4; ++i)
#pragma unroll
        for (int j = 0; j < 4; ++j)
            acc[i][j] = (f32x4){0.f, 0.f, 0.f, 0.f};

    for (int kt = k0; kt < k0 + klen; kt += BK) {
#pragma unroll
        for (int p = 0; p < 4; ++p)
            gload16(gA0 + ((size_t)p * 8 * K + kt) * 2, lA0 + p * 1024);
#pragma unroll
        for (int p = 0; p < 4; ++p)
            gload16(gB0 + ((size_t)p * 8 * K + kt) * 2, lB0 + p * 1024);
        __syncthreads();
#pragma unroll
        for (int kk = 0; kk < BK / 32; ++kk) {
            bf16x8 af[4], bfr[4];
#pragma unroll
            for (int i = 0; i < 4; ++i) {
                int row = wm + i * 16 + l16;
                int byt = (row * 128 + kk * 64 + lhi * 16) ^ ((row & 7) << 4);
                af[i] = *(const bf16x8*)(lds_a + byt);
            }
#pragma unroll
            for (int j = 0; j < 4; ++j) {
                int row = wn + j * 16 + l16;
                int byt = (row * 128 + kk * 64 + lhi * 16) ^ ((row & 7) << 4);
                bfr[j] = *(const bf16x8*)(lds_b + byt);
            }
#pragma unroll
            for (int i = 0; i < 4; ++i)
#pragma unroll
                for (int j = 0; j < 4; ++j)
                    acc[i][j] = __builtin_amdgcn_mfma_f32_16x16x32_bf16(af[i], bfr[j], acc[i][j], 0, 0, 0);
        }
        __syncthreads();
    }

    const size_t obase = (size_t)bz * (size_t)sO;
    if constexpr (!TRANS) {
#pragma unroll
        for (int i = 0; i < 4; ++i) {
            const int m0 = bm + wm + i * 16 + lhi * 4;
#pragma unroll
            for (int j = 0; j < 4; ++j) {
                const int n = bn + wn + j * 16 + l16;
#pragma unroll
                for (int r = 0; r < 4; ++r) {
                    float v = acc[i][j][r];
                    if constexpr (RELU) v = fmaxf(v, 0.f);
                    size_t addr = obase + (size_t)(m0 + r) * N + n;
                    if constexpr (OUT_F32) ((float*)Op)[addr] = v;
                    else ((unsigned short*)Op)[addr] = f2bf(v);
                }
            }
        }
    } else {
#pragma unroll
        for (int i = 0; i < 4; ++i) {
            const int m0 = bm + wm + i * 16 + lhi * 4;
#pragma unroll
            for (int j = 0; j < 4; ++j) {
                const int n = bn + wn + j * 16 + l16;
                u16x4 h;
#pragma unroll
                for (int r = 0; r < 4; ++r) {
                    float v = acc[i][j][r];
                    if constexpr (RELU) v = fmaxf(v, 0.f);
                    h[r] = f2bf(v);
                }
                *(u16x4*)((unsigned short*)Op + obase + (size_t)n * M + m0) = h;
            }
        }
    }
}

// ---------------- 256x256 8-phase kernel, post-MFMA read-ahead (round 9b) ----------------
// Phase p: LGKM0; 16 MFMA (frags read in phase p-1, drained by this LGKM0);
//          issue phase-(p+1)'s ds_reads AFTER the mm that last consumes the
//          destination regs (no extra registers, WAR handled by compiler);
//          stage slots; counted vmcnt gates; BAR.
// Hazard ledger (verified):
//  restage >= drain(last read)+barrier:  B0'@P3 (last rd P1-post, drain P2-LGKM0,
//  P2-BAR); A0'@P4/P5 (last rd P2-post); B1'@P7/P8 (last rd P5-post);
//  A1(t1)[1]@P1 (last rd prev-P6-post).
//  first-read gates (vmcnt certifies all but newest N; barrier before read):
//  VM4@P2 -> buf1-B (rd P3-post); VM2@P3(after stage) -> buf1-A incl [1]
//  (rd P4-post by wm=128 waves); VM4@P6 -> buf0-B (rd P7-post);
//  VM2@P7(after stage) -> buf0-A (rd P8-post). Never vmcnt(0) in loop.
#define CTILE 65536
#define CBOFF 32768

template<bool OUT_F32, bool TRANS, bool RELU>
__global__ __launch_bounds__(512, 2)
void gemm256(const unsigned short* __restrict__ Ap, const unsigned short* __restrict__ Bp,
             void* __restrict__ Op, int M, int N, int K, int klen, int split,
             long long sA, long long sB, long long sO)
{
    __shared__ char lds[131072];
    const int tid  = threadIdx.x;
    const int wave = tid >> 6;
    const int lane = tid & 63;

    // XCD-aware bijective block swizzle (all grids have nwg % 8 == 0)
    const int gx = gridDim.x, gy = gridDim.y;
    const int f   = blockIdx.x + gx * (blockIdx.y + gy * blockIdx.z);
    const int nwg = gx * gy * (int)gridDim.z;
    const int s   = (f & 7) * (nwg >> 3) + (f >> 3);
    const int lx  = s % gx;
    const int lyz = s / gx;
    const int ly  = lyz % gy;
    const int lz  = lyz / gy;

    const int batch = lz / split;
    const int k0    = (lz % split) * klen;
    const int bm    = ly * 256;
    const int bn    = lx * 256;

    const int wm  = (wave >> 2) * 128;
    const int wn  = (wave & 3) * 64;
    const int l16 = lane & 15, lhi = lane >> 4;

    const unsigned short* Abase = Ap + (size_t)batch * sA + (size_t)bm * K;
    const unsigned short* Bbase = Bp + (size_t)batch * sB + (size_t)bn * K;
    const int srow  = lane >> 3;
    const int schnk = (lane & 7) ^ srow;
    const size_t K2 = (size_t)K * 2;
    const char* gA = (const char*)Abase + (size_t)srow * K2 + (size_t)schnk * 16 + (size_t)k0 * 2;
    const char* gB = (const char*)Bbase + (size_t)srow * K2 + (size_t)schnk * 16 + (size_t)k0 * 2;

    f32x4 acc[8][4];
#pragma unroll
    for (int i = 0; i < 8; ++i)
#pragma unroll
        for (int j = 0; j < 4; ++j)
            acc[i][j] = (f32x4){0.f, 0.f, 0.f, 0.f};

    bf16x8 a[4][2], b0[2][2], b1[2][2];

    auto stageA2 = [&](int c, int t, int h) {
#pragma unroll
        for (int p = 0; p < 2; ++p)
            gload16(gA + (size_t)t * 128 + (size_t)(h * 128 + wave * 16 + p * 8) * K2,
                    lds + c * CTILE + h * 16384 + wave * 2048 + p * 1024);
    };
    auto stageB2 = [&](int c, int t, int h) {
#pragma unroll
        for (int p = 0; p < 2; ++p)
            gload16(gB + (size_t)t * 128 + (size_t)(h * 128 + wave * 16 + p * 8) * K2,
                    lds + c * CTILE + CBOFF + h * 16384 + wave * 2048 + p * 1024);
    };
    auto ldA = [&](int c, int mh) {
#pragma unroll
        for (int i4 = 0; i4 < 4; ++i4)
#pragma unroll
            for (int kk = 0; kk < 2; ++kk) {
                int row = wm + mh * 64 + i4 * 16 + l16;
                int byt = (row * 128 + kk * 64 + lhi * 16) ^ ((row & 7) << 4);
                a[i4][kk] = *(const bf16x8*)(lds + c * CTILE + byt);
            }
    };
    auto ldB = [&](int c, int nh, bf16x8 (&bb)[2][2]) {
#pragma unroll
        for (int j2 = 0; j2 < 2; ++j2)
#pragma unroll
            for (int kk = 0; kk < 2; ++kk) {
                int row = wn + nh * 32 + j2 * 16 + l16;
                int byt = (row * 128 + kk * 64 + lhi * 16) ^ ((row & 7) << 4);
                bb[j2][kk] = *(const bf16x8*)(lds + c * CTILE + CBOFF + byt);
            }
    };
    auto mm = [&](int mh, int nh, bf16x8 (&bb)[2][2]) {
        __builtin_amdgcn_s_setprio(1);
#pragma unroll
        for (int i4 = 0; i4 < 4; ++i4)
#pragma unroll
            for (int j2 = 0; j2 < 2; ++j2)
#pragma unroll
                for (int kk = 0; kk < 2; ++kk)
                    acc[mh * 4 + i4][nh * 2 + j2] = __builtin_amdgcn_mfma_f32_16x16x32_bf16(
                        a[i4][kk], bb[j2][kk], acc[mh * 4 + i4][nh * 2 + j2], 0, 0, 0);
        __builtin_amdgcn_s_setprio(0);
    };

#define BAR()   __builtin_amdgcn_s_barrier()
#define LGKM0() asm volatile("s_waitcnt lgkmcnt(0)" ::: "memory")
#define VM2()   asm volatile("s_waitcnt vmcnt(2)" ::: "memory")
#define VM4()   asm volatile("s_waitcnt vmcnt(4)" ::: "memory")
#define VM6()   asm volatile("s_waitcnt vmcnt(6)" ::: "memory")

    const int NT = klen / 64;
    // prologue: buf0 full (8), buf1 B full + A half0 (6); A1(t=1)[1] staged at P1.
    stageB2(0, 0, 0); stageB2(0, 0, 1); stageA2(0, 0, 0); stageA2(0, 0, 1);
    stageB2(1, 1, 0); stageB2(1, 1, 1); stageA2(1, 1, 0);
    VM6();             // certify buf0's 8; keep buf1's 6 in flight
    BAR();
    ldB(0, 0, b0); ldA(0, 0);        // R for P1 (drain at P1's LGKM0)

    for (int itr = 0; itr < NT / 2; ++itr) {
        const int t1  = 2 * itr + 1;
        const int tp0 = (2 * itr + 2) % NT;
        const int tp1 = (2 * itr + 3) % NT;
        // P1
        LGKM0(); mm(0, 0, b0);
        ldB(0, 1, b1); stageA2(1, t1, 1);
        BAR();
        // P2
        LGKM0(); mm(0, 1, b1);
        ldA(0, 1); VM4();
        BAR();
        // P3
        LGKM0(); mm(1, 0, b0);
        ldB(1, 0, b0); stageB2(0, tp0, 0); VM2();
        BAR();
        // P4
        LGKM0(); mm(1, 1, b1);
        ldA(1, 0); stageB2(0, tp0, 1); stageA2(0, tp0, 0);
        BAR();
        // P5
        LGKM0(); mm(0, 0, b0);
        ldB(1, 1, b1); stageA2(0, tp0, 1);
        BAR();
        // P6
        LGKM0(); mm(0, 1, b1);
        ldA(1, 1); VM4();
        BAR();
        // P7
        LGKM0(); mm(1, 0, b0);
        ldB(0, 0, b0); stageB2(1, tp1, 0); VM2();
        BAR();
        // P8
        LGKM0(); mm(1, 1, b1);
        ldA(0, 0); stageB2(1, tp1, 1); stageA2(1, tp1, 0);
        BAR();
    }
    asm volatile("s_waitcnt vmcnt(0)" ::: "memory");

    const size_t obase = (size_t)lz * (size_t)sO;
    if constexpr (!TRANS) {
#pragma unroll
        for (int i = 0; i < 8; ++i) {
            const int m0 = bm + wm + i * 16 + lhi * 4;
#pragma unroll
            for (int j = 0; j < 4; ++j) {
                const int n = bn + wn + j * 16 + l16;
#pragma unroll
                for (int r = 0; r < 4; ++r) {
                    float v = acc[i][j][r];
                    if constexpr (RELU) v = fmaxf(v, 0.f);
                    size_t addr = obase + (size_t)(m0 + r) * N + n;
                    if constexpr (OUT_F32) ((float*)Op)[addr] = v;
                    else ((unsigned short*)Op)[addr] = f2bf(v);
                }
            }
        }
    } else {
#pragma unroll
        for (int i = 0; i < 8; ++i) {
            const int m0 = bm + wm + i * 16 + lhi * 4;
#pragma unroll
            for (int j = 0; j < 4; ++j) {
                const int n = bn + wn + j * 16 + l16;
                u16x4 h;
#pragma unroll
                for (int r = 0; r < 4; ++r) {
                    float v = acc[i][j][r];
                    if constexpr (RELU) v = fmaxf(v, 0.f);
                    h[r] = f2bf(v);
                }
                *(u16x4*)((unsigned short*)Op + obase + (size_t)n * M + m0) = h;
            }
        }
    }
#undef BAR
#undef LGKM0
#undef VM2
#undef VM4
#undef VM6
}

extern "C" void kernel_launch(void* const* d_in, const int* in_sizes, int n_in,
                              void* d_out, int out_size, void* d_ws, size_t ws_size,
                              hipStream_t stream) {
    (void)in_sizes; (void)n_in; (void)out_size; (void)ws_size;
    const float* x  = (const float*)d_in[0];
    const float* Wa = (const float*)d_in[1];
    const float* Wb = (const float*)d_in[2];
    const float* Wc = (const float*)d_in[3];
    const float* Wd = (const float*)d_in[4];

    const long long SD  = (long long)S_ * D_;
    const long long DD2 = (long long)D_ * D_;
    const size_t MB = 1024 * 1024;

    // ws (64MB): fused BC output [b][2048][S] bf16 = 64MB exactly.
    //   After E: BC dead -> A @0-32MB, Ft @32-40MB.
    unsigned short* BC = (unsigned short*)d_ws;
    unsigned short* Ao = (unsigned short*)d_ws;
    unsigned short* Ft = (unsigned short*)((char*)d_ws + 32 * MB);
    // d_out scratch (64MB): xb@0-32 | P (16 segs x 2MB) @32-64.
    //   Wbb@56,Wcb@58 die after projBC (overwritten by P segs 12-15).
    //   After reduce: Enorm[b] in-place at P[4b]; dead segs 1-2 -> Wdb@34, Wab@36.
    char* ob = (char*)d_out;
    unsigned short* xb    = (unsigned short*)ob;
    unsigned short* Pp    = (unsigned short*)(ob + 32 * MB);
    unsigned short* Enorm = Pp;                              // batch stride 4*DD2
    unsigned short* Wdb   = (unsigned short*)(ob + 34 * MB);
    unsigned short* Wab   = (unsigned short*)(ob + 36 * MB);
    unsigned short* Wbb   = (unsigned short*)(ob + 56 * MB); // Wbb|Wcb contiguous
    unsigned short* Wcb   = (unsigned short*)(ob + 58 * MB);

    dim3 blk256(256, 1, 1);
    dim3 blk512(512, 1, 1);
    dim3 gBC(2048 / 256, S_ / 256, B_);        // (8,16,4) = 512
    dim3 gE(D_ / 256, D_ / 256, B_ * 4);       // (4,4,16) = 256, split-K=4
    dim3 gS(D_ / 256, S_ / 256, B_);           // (4,16,4) = 256
    dim3 gF(D_ / BN, D_ / BM, B_);             // (8,8,4)

    // 0) convert x and Wb|Wc
    conv_bf16<<<2048, blk256, 0, stream>>>(x, xb, (B_ * S_ * D_) / 8);
    conv_bf16_w2<<<512, blk256, 0, stream>>>(Wb, Wc, Wbb, Wcb, (D_ * D_) / 8);
    // 1) fused projections: BC[b][n][s] = relu(xb [Wb;Wc]^T)^T, n in [0,2048)
    gemm256<false, true,  true ><<<gBC, blk512, 0, stream>>>(xb, Wbb, BC, S_, 2048, D_, D_, 1, SD, 0, 2 * SD);
    // 2) E partials: P[b*4+seg] = sum_{s in seg} Bm[s,e] C[s,e']
    gemm256<false, false, false><<<gE, blk512, 0, stream>>>(BC, BC + SD, Pp, D_, D_, S_, S_ / 4, 4, 2 * SD, 2 * SD, DD2);
    // 2b) Enorm[b] = sum_seg P  (in-place at P[4b])
    reduceN_bf16_inplace<<<2048, blk256, 0, stream>>>(Pp, 4, (B_ * D_ * D_) / 8);
    // 2c) convert Wd, Wa into dead P segs 1-2
    conv_bf16_w2<<<512, blk256, 0, stream>>>(Wd, Wa, Wdb, Wab, (D_ * D_) / 8);
    // 3) Ft[b][dout][e] = (Enorm[b] @ Wd^T)^T
    gemm_nt<false, true,  false><<<gF, blk256, 0, stream>>>(Enorm, Wdb, Ft, D_, D_, D_, D_, 1, 4 * DD2, 0, DD2);
    // 4) A[b][s][e] = relu(xb Wa^T) -> ws@0 (BC dead)
    gemm256<false, false, true ><<<gS, blk512, 0, stream>>>(xb, Wab, Ao, S_, D_, D_, D_, 1, SD, 0, SD);
    // 5) out = relu(A @ Ft-rows) f32 -> d_out (reads only ws; overwrites d_out)
    gemm256<true,  false, true ><<<gS, blk512, 0, stream>>>(Ao, Ft, (float*)d_out, S_, D_, D_, D_, 1, SD, DD2, SD);
}

// Round 12
// 242.025 us; speedup vs baseline: 2.0663x; 1.0057x over previous
//
#include <hip/hip_runtime.h>
#include <hip/hip_bf16.h>

#define D_ 1024
#define B_ 4
#define S_ 4096

typedef __attribute__((ext_vector_type(8))) short bf16x8;
typedef __attribute__((ext_vector_type(4))) float f32x4;
typedef __attribute__((ext_vector_type(4))) unsigned int u32x4;
typedef __attribute__((ext_vector_type(4))) unsigned short u16x4;

__device__ __forceinline__ unsigned short f2bf(float f) {
    unsigned int u = __builtin_bit_cast(unsigned int, f);
    u = u + 0x7fffu + ((u >> 16) & 1u);
    return (unsigned short)(u >> 16);
}
__device__ __forceinline__ unsigned int pk2(float a, float b) {
    return (unsigned int)f2bf(a) | ((unsigned int)f2bf(b) << 16);
}
__device__ __forceinline__ float bf2f(unsigned short h) {
    unsigned int u = ((unsigned int)h) << 16;
    return __builtin_bit_cast(float, u);
}
__device__ __forceinline__ void gload16(const void* g, void* l) {
    __builtin_amdgcn_global_load_lds(
        (const __attribute__((address_space(1))) void*)g,
        (__attribute__((address_space(3))) void*)l, 16, 0, 0);
}

// ---------------- elementwise helpers ----------------
__global__ __launch_bounds__(256)
void conv_bf16(const float* __restrict__ src, unsigned short* __restrict__ dst, int n8) {
    int i = blockIdx.x * blockDim.x + threadIdx.x;
    const int stride = gridDim.x * blockDim.x;
    for (; i < n8; i += stride) {
        f32x4 v0 = *(const f32x4*)(src + (size_t)i * 8);
        f32x4 v1 = *(const f32x4*)(src + (size_t)i * 8 + 4);
        u32x4 o;
        o[0] = pk2(v0[0], v0[1]);
        o[1] = pk2(v0[2], v0[3]);
        o[2] = pk2(v1[0], v1[1]);
        o[3] = pk2(v1[2], v1[3]);
        *(u32x4*)(dst + (size_t)i * 8) = o;
    }
}

__global__ __launch_bounds__(256)
void conv_bf16_w2(const float* __restrict__ s0, const float* __restrict__ s1,
                  unsigned short* __restrict__ d0, unsigned short* __restrict__ d1,
                  int n8_per) {
    int i = blockIdx.x * blockDim.x + threadIdx.x;
    const int stride = gridDim.x * blockDim.x;
    for (; i < 2 * n8_per; i += stride) {
        int w = i / n8_per;
        size_t j = (size_t)(i - w * n8_per) * 8;
        const float* s = w ? s1 : s0;
        unsigned short* d = w ? d1 : d0;
        f32x4 v0 = *(const f32x4*)(s + j);
        f32x4 v1 = *(const f32x4*)(s + j + 4);
        u32x4 o;
        o[0] = pk2(v0[0], v0[1]);
        o[1] = pk2(v0[2], v0[3]);
        o[2] = pk2(v1[0], v1[1]);
        o[3] = pk2(v1[2], v1[3]);
        *(u32x4*)(d + j) = o;
    }
}

// In-place segment reduce: E[b][i] = sum_seg P[b*split+seg][i], E stored at P[b*split].
__global__ __launch_bounds__(256)
void reduceN_bf16_inplace(unsigned short* __restrict__ P, int split, int n8_total) {
    int t = blockIdx.x * blockDim.x + threadIdx.x;
    const int stride = gridDim.x * blockDim.x;
    const int DD = D_ * D_;
    for (; t < n8_total; t += stride) {
        size_t idx = (size_t)t * 8;
        int b = (int)(idx / DD);
        size_t i = idx % DD;
        float s[8];
#pragma unroll
        for (int k = 0; k < 8; ++k) s[k] = 0.f;
        for (int seg = 0; seg < split; ++seg) {
            const unsigned short* p = P + (size_t)(b * split + seg) * DD + i;
            u16x4 v0 = *(const u16x4*)p;
            u16x4 v1 = *(const u16x4*)(p + 4);
#pragma unroll
            for (int k = 0; k < 4; ++k) { s[k] += bf2f(v0[k]); s[4 + k] += bf2f(v1[k]); }
        }
        u16x4 o0, o1;
#pragma unroll
        for (int k = 0; k < 4; ++k) { o0[k] = f2bf(s[k]); o1[k] = f2bf(s[4 + k]); }
        unsigned short* e = P + (size_t)(b * split) * DD + i;
        *(u16x4*)e = o0;
        *(u16x4*)(e + 4) = o1;
    }
}

// ---------------- 128x128 2-phase kernel (proven; small F-GEMM only) ----------------
#define BM 128
#define BN 128
#define BK 64
#define NTHR 256

template<bool OUT_F32, bool TRANS, bool RELU>
__global__ __launch_bounds__(NTHR)
void gemm_nt(const unsigned short* __restrict__ Ap, const unsigned short* __restrict__ Bp,
             void* __restrict__ Op, int M, int N, int K, int klen, int split,
             long long sA, long long sB, long long sO)
{
    __shared__ char lds_a[BM * BK * 2];
    __shared__ char lds_b[BN * BK * 2];

    const int tid   = threadIdx.x;
    const int bz    = blockIdx.z;
    const int batch = bz / split;
    const int k0    = (bz % split) * klen;
    const int bm    = blockIdx.y * BM;
    const int bn    = blockIdx.x * BN;

    const unsigned short* Abase = Ap + (size_t)batch * sA + (size_t)bm * K;
    const unsigned short* Bbase = Bp + (size_t)batch * sB + (size_t)bn * K;

    const int lane = tid & 63;
    const int wave = tid >> 6;
    const int wm   = (wave >> 1) * 64;
    const int wn   = (wave & 1) * 64;
    const int l16  = lane & 15;
    const int lhi  = lane >> 4;

    const int schnk = (lane & 7) ^ (lane >> 3);
    const char* gA0 = (const char*)(Abase + (size_t)(wave * 32 + (lane >> 3)) * K) + schnk * 16;
    const char* gB0 = (const char*)(Bbase + (size_t)(wave * 32 + (lane >> 3)) * K) + schnk * 16;
    char* lA0 = lds_a + wave * 4096;
    char* lB0 = lds_b + wave * 4096;

    f32x4 acc[4][4];
#pragma unroll
    for (int i = 0; i < 4; ++i)
#pragma unroll
        for (int j = 0; j < 4; ++j)
            acc[i][j] = (f32x4){0.f, 0.f, 0.f, 0.f};

    for (int kt = k0; kt < k0 + klen; kt += BK) {
#pragma unroll
        for (int p = 0; p < 4; ++p)
            gload16(gA0 + ((size_t)p * 8 * K + kt) * 2, lA0 + p * 1024);
#pragma unroll
        for (int p = 0; p < 4; ++p)
            gload16(gB0 + ((size_t)p * 8 * K + kt) * 2, lB0 + p * 1024);
        __syncthreads();
#pragma unroll
        for (int kk = 0; kk < BK / 32; ++kk) {
            bf16x8 af[4], bfr[4];
#pragma unroll
            for (int i = 0; i < 4; ++i) {
                int row = wm + i * 16 + l16;
                int byt = (row * 128 + kk * 64 + lhi * 16) ^ ((row & 7) << 4);
                af[i] = *(const bf16x8*)(lds_a + byt);
            }
#pragma unroll
            for (int j = 0; j < 4; ++j) {
                int row = wn + j * 16 + l16;
                int byt = (row * 128 + kk * 64 + lhi * 16) ^ ((row & 7) << 4);
                bfr[j] = *(const bf16x8*)(lds_b + byt);
            }
#pragma unroll
            for (int i = 0; i < 4; ++i)
#pragma unroll
                for (int j = 0; j < 4; ++j)
                    acc[i][j] = __builtin_amdgcn_mfma_f32_16x16x32_bf16(af[i], bfr[j], acc[i][j], 0, 0, 0);
        }
        __syncthreads();
    }

    const size_t obase = (size_t)bz * (size_t)sO;
    if constexpr (!TRANS) {
#pragma unroll
        for (int i = 0; i < 4; ++i) {
            const int m0 = bm + wm + i * 16 + lhi * 4;
#pragma unroll
            for (int j = 0; j < 4; ++j) {
                const int n = bn + wn + j * 16 + l16;
#pragma unroll
                for (int r = 0; r < 4; ++r) {
                    float v = acc[i][j][r];
                    if constexpr (RELU) v = fmaxf(v, 0.f);
                    size_t addr = obase + (size_t)(m0 + r) * N + n;
                    if constexpr (OUT_F32) ((float*)Op)[addr] = v;
                    else ((unsigned short*)Op)[addr] = f2bf(v);
                }
            }
        }
    } else {
#pragma unroll
        for (int i = 0; i < 4; ++i) {
            const int m0 = bm + wm + i * 16 + lhi * 4;
#pragma unroll
            for (int j = 0; j < 4; ++j) {
                const int n = bn + wn + j * 16 + l16;
                u16x4 h;
#pragma unroll
                for (int r = 0; r < 4; ++r) {
                    float v = acc[i][j][r];
                    if constexpr (RELU) v = fmaxf(v, 0.f);
                    h[r] = f2bf(v);
                }
                *(u16x4*)((unsigned short*)Op + obase + (size_t)n * M + m0) = h;
            }
        }
    }
}

// ---------------- 256x256 8-phase kernel, post-MFMA read-ahead (round 12) ----------------
// Schedule/sync identical to r10 (verified 243us, absmax 4096). LDS addressing
// strength-reduced to base+immediate, FIXED from r11: kk*64 must sit INSIDE the
// swizzle XOR (bit 6 overlaps the mask (l16&7)<<4). Valid decomposition:
//   addr = [ ((wX+l16)*128 + kk*64 + lhi*16) ^ lxor ]  +  (frag)*2048*k
// where the added immediates are multiples of 2048 (bits >=11), which cannot
// interact with XOR bits 4-6. 8 base pointers, all reads single-instruction.
#define CTILE 65536
#define CBOFF 32768

template<bool OUT_F32, bool TRANS, bool RELU>
__global__ __launch_bounds__(512, 2)
void gemm256(const unsigned short* __restrict__ Ap, const unsigned short* __restrict__ Bp,
             void* __restrict__ Op, int M, int N, int K, int klen, int split,
             long long sA, long long sB, long long sO)
{
    __shared__ char lds[131072];
    const int tid  = threadIdx.x;
    const int wave = tid >> 6;
    const int lane = tid & 63;

    // XCD-aware bijective block swizzle (all grids have nwg % 8 == 0)
    const int gx = gridDim.x, gy = gridDim.y;
    const int f   = blockIdx.x + gx * (blockIdx.y + gy * blockIdx.z);
    const int nwg = gx * gy * (int)gridDim.z;
    const int s   = (f & 7) * (nwg >> 3) + (f >> 3);
    const int lx  = s % gx;
    const int lyz = s / gx;
    const int ly  = lyz % gy;
    const int lz  = lyz / gy;

    const int batch = lz / split;
    const int k0    = (lz % split) * klen;
    const int bm    = ly * 256;
    const int bn    = lx * 256;

    const int wm  = (wave >> 2) * 128;
    const int wn  = (wave & 3) * 64;
    const int l16 = lane & 15, lhi = lane >> 4;

    const unsigned short* Abase = Ap + (size_t)batch * sA + (size_t)bm * K;
    const unsigned short* Bbase = Bp + (size_t)batch * sB + (size_t)bn * K;
    const int srow  = lane >> 3;
    const int schnk = (lane & 7) ^ srow;
    const size_t K2 = (size_t)K * 2;
    const char* gA = (const char*)Abase + (size_t)srow * K2 + (size_t)schnk * 16 + (size_t)k0 * 2;
    const char* gB = (const char*)Bbase + (size_t)srow * K2 + (size_t)schnk * 16 + (size_t)k0 * 2;

    // lane-constant LDS read bases; kk*64 folded INSIDE the XOR (bit-6 overlap)
    const int lxor = (l16 & 7) << 4;
    const int aX = (wm + l16) * 128 + lhi * 16;
    const int bX = (wn + l16) * 128 + lhi * 16;
    const char* aB00 = lds + 0 * CTILE + ((aX + 0 * 64) ^ lxor);
    const char* aB01 = lds + 0 * CTILE + ((aX + 1 * 64) ^ lxor);
    const char* aB10 = lds + 1 * CTILE + ((aX + 0 * 64) ^ lxor);
    const char* aB11 = lds + 1 * CTILE + ((aX + 1 * 64) ^ lxor);
    const char* bB00 = lds + 0 * CTILE + CBOFF + ((bX + 0 * 64) ^ lxor);
    const char* bB01 = lds + 0 * CTILE + CBOFF + ((bX + 1 * 64) ^ lxor);
    const char* bB10 = lds + 1 * CTILE + CBOFF + ((bX + 0 * 64) ^ lxor);
    const char* bB11 = lds + 1 * CTILE + CBOFF + ((bX + 1 * 64) ^ lxor);

    f32x4 acc[8][4];
#pragma unroll
    for (int i = 0; i < 8; ++i)
#pragma unroll
        for (int j = 0; j < 4; ++j)
            acc[i][j] = (f32x4){0.f, 0.f, 0.f, 0.f};

    bf16x8 a[4][2], b0[2][2], b1[2][2];

    auto stageA2 = [&](int c, int t, int h) {
#pragma unroll
        for (int p = 0; p < 2; ++p)
            gload16(gA + (size_t)t * 128 + (size_t)(h * 128 + wave * 16 + p * 8) * K2,
                    lds + c * CTILE + h * 16384 + wave * 2048 + p * 1024);
    };
    auto stageB2 = [&](int c, int t, int h) {
#pragma unroll
        for (int p = 0; p < 2; ++p)
            gload16(gB + (size_t)t * 128 + (size_t)(h * 128 + wave * 16 + p * 8) * K2,
                    lds + c * CTILE + CBOFF + h * 16384 + wave * 2048 + p * 1024);
    };
    auto ldA = [&](int c, int mh) {
        const char* base0 = c ? aB10 : aB00;
        const char* base1 = c ? aB11 : aB01;
#pragma unroll
        for (int i4 = 0; i4 < 4; ++i4) {
            const int imm = (mh * 64 + i4 * 16) * 128;   // multiple of 2048
            a[i4][0] = *(const bf16x8*)(base0 + imm);
            a[i4][1] = *(const bf16x8*)(base1 + imm);
        }
    };
    auto ldB = [&](int c, int nh, bf16x8 (&bb)[2][2]) {
        const char* base0 = c ? bB10 : bB00;
        const char* base1 = c ? bB11 : bB01;
#pragma unroll
        for (int j2 = 0; j2 < 2; ++j2) {
            const int imm = (nh * 32 + j2 * 16) * 128;   // multiple of 2048
            bb[j2][0] = *(const bf16x8*)(base0 + imm);
            bb[j2][1] = *(const bf16x8*)(base1 + imm);
        }
    };
    auto mm = [&](int mh, int nh, bf16x8 (&bb)[2][2]) {
        __builtin_amdgcn_s_setprio(1);
#pragma unroll
        for (int i4 = 0; i4 < 4; ++i4)
#pragma unroll
            for (int j2 = 0; j2 < 2; ++j2)
#pragma unroll
                for (int kk = 0; kk < 2; ++kk)
                    acc[mh * 4 + i4][nh * 2 + j2] = __builtin_amdgcn_mfma_f32_16x16x32_bf16(
                        a[i4][kk], bb[j2][kk], acc[mh * 4 + i4][nh * 2 + j2], 0, 0, 0);
        __builtin_amdgcn_s_setprio(0);
    };

#define BAR()   __builtin_amdgcn_s_barrier()
#define LGKM0() asm volatile("s_waitcnt lgkmcnt(0)" ::: "memory")
#define VM2()   asm volatile("s_waitcnt vmcnt(2)" ::: "memory")
#define VM4()   asm volatile("s_waitcnt vmcnt(4)" ::: "memory")
#define VM6()   asm volatile("s_waitcnt vmcnt(6)" ::: "memory")

    const int NT = klen / 64;
    // prologue: buf0 full (8), buf1 B full + A half0 (6); A1(t=1)[1] staged at P1.
    stageB2(0, 0, 0); stageB2(0, 0, 1); stageA2(0, 0, 0); stageA2(0, 0, 1);
    stageB2(1, 1, 0); stageB2(1, 1, 1); stageA2(1, 1, 0);
    VM6();             // certify buf0's 8; keep buf1's 6 in flight
    BAR();
    ldB(0, 0, b0); ldA(0, 0);        // R for P1 (drain at P1's LGKM0)

    for (int itr = 0; itr < NT / 2; ++itr) {
        const int t1  = 2 * itr + 1;
        const int tp0 = (2 * itr + 2) % NT;
        const int tp1 = (2 * itr + 3) % NT;
        // P1
        LGKM0(); mm(0, 0, b0);
        ldB(0, 1, b1); stageA2(1, t1, 1);
        BAR();
        // P2
        LGKM0(); mm(0, 1, b1);
        ldA(0, 1); VM4();
        BAR();
        // P3
        LGKM0(); mm(1, 0, b0);
        ldB(1, 0, b0); stageB2(0, tp0, 0); VM2();
        BAR();
        // P4
        LGKM0(); mm(1, 1, b1);
        ldA(1, 0); stageB2(0, tp0, 1); stageA2(0, tp0, 0);
        BAR();
        // P5
        LGKM0(); mm(0, 0, b0);
        ldB(1, 1, b1); stageA2(0, tp0, 1);
        BAR();
        // P6
        LGKM0(); mm(0, 1, b1);
        ldA(1, 1); VM4();
        BAR();
        // P7
        LGKM0(); mm(1, 0, b0);
        ldB(0, 0, b0); stageB2(1, tp1, 0); VM2();
        BAR();
        // P8
        LGKM0(); mm(1, 1, b1);
        ldA(0, 0); stageB2(1, tp1, 1); stageA2(1, tp1, 0);
        BAR();
    }
    asm volatile("s_waitcnt vmcnt(0)" ::: "memory");

    const size_t obase = (size_t)lz * (size_t)sO;
    if constexpr (!TRANS) {
#pragma unroll
        for (int i = 0; i < 8; ++i) {
            const int m0 = bm + wm + i * 16 + lhi * 4;
#pragma unroll
            for (int j = 0; j < 4; ++j) {
                const int n = bn + wn + j * 16 + l16;
#pragma unroll
                for (int r = 0; r < 4; ++r) {
                    float v = acc[i][j][r];
                    if constexpr (RELU) v = fmaxf(v, 0.f);
                    size_t addr = obase + (size_t)(m0 + r) * N + n;
                    if constexpr (OUT_F32) ((float*)Op)[addr] = v;
                    else ((unsigned short*)Op)[addr] = f2bf(v);
                }
            }
        }
    } else {
#pragma unroll
        for (int i = 0; i < 8; ++i) {
            const int m0 = bm + wm + i * 16 + lhi * 4;
#pragma unroll
            for (int j = 0; j < 4; ++j) {
                const int n = bn + wn + j * 16 + l16;
                u16x4 h;
#pragma unroll
                for (int r = 0; r < 4; ++r) {
                    float v = acc[i][j][r];
                    if constexpr (RELU) v = fmaxf(v, 0.f);
                    h[r] = f2bf(v);
                }
                *(u16x4*)((unsigned short*)Op + obase + (size_t)n * M + m0) = h;
            }
        }
    }
#undef BAR
#undef LGKM0
#undef VM2
#undef VM4
#undef VM6
}

extern "C" void kernel_launch(void* const* d_in, const int* in_sizes, int n_in,
                              void* d_out, int out_size, void* d_ws, size_t ws_size,
                              hipStream_t stream) {
    (void)in_sizes; (void)n_in; (void)out_size; (void)ws_size;
    const float* x  = (const float*)d_in[0];
    const float* Wa = (const float*)d_in[1];
    const float* Wb = (const float*)d_in[2];
    const float* Wc = (const float*)d_in[3];
    const float* Wd = (const float*)d_in[4];

    const long long SD  = (long long)S_ * D_;
    const long long DD2 = (long long)D_ * D_;
    const size_t MB = 1024 * 1024;

    // ws (64MB): fused BC output [b][2048][S] bf16 = 64MB exactly.
    //   After E: BC dead -> A @0-32MB, Ft @32-40MB.
    unsigned short* BC = (unsigned short*)d_ws;
    unsigned short* Ao = (unsigned short*)d_ws;
    unsigned short* Ft = (unsigned short*)((char*)d_ws + 32 * MB);
    // d_out scratch (64MB): xb@0-32 | P (16 segs x 2MB) @32-64.
    //   Wbb@56,Wcb@58 die after projBC (overwritten by P segs 12-15).
    //   After reduce: Enorm[b] in-place at P[4b]; dead segs 1-2 -> Wdb@34, Wab@36.
    char* ob = (char*)d_out;
    unsigned short* xb    = (unsigned short*)ob;
    unsigned short* Pp    = (unsigned short*)(ob + 32 * MB);
    unsigned short* Enorm = Pp;                              // batch stride 4*DD2
    unsigned short* Wdb   = (unsigned short*)(ob + 34 * MB);
    unsigned short* Wab   = (unsigned short*)(ob + 36 * MB);
    unsigned short* Wbb   = (unsigned short*)(ob + 56 * MB); // Wbb|Wcb contiguous
    unsigned short* Wcb   = (unsigned short*)(ob + 58 * MB);

    dim3 blk256(256, 1, 1);
    dim3 blk512(512, 1, 1);
    dim3 gBC(2048 / 256, S_ / 256, B_);        // (8,16,4) = 512
    dim3 gE(D_ / 256, D_ / 256, B_ * 4);       // (4,4,16) = 256, split-K=4
    dim3 gS(D_ / 256, S_ / 256, B_);           // (4,16,4) = 256
    dim3 gF(D_ / BN, D_ / BM, B_);             // (8,8,4)

    // 0) convert x and Wb|Wc
    conv_bf16<<<2048, blk256, 0, stream>>>(x, xb, (B_ * S_ * D_) / 8);
    conv_bf16_w2<<<512, blk256, 0, stream>>>(Wb, Wc, Wbb, Wcb, (D_ * D_) / 8);
    // 1) fused projections: BC[b][n][s] = relu(xb [Wb;Wc]^T)^T, n in [0,2048)
    gemm256<false, true,  true ><<<gBC, blk512, 0, stream>>>(xb, Wbb, BC, S_, 2048, D_, D_, 1, SD, 0, 2 * SD);
    // 2) E partials: P[b*4+seg] = sum_{s in seg} Bm[s,e] C[s,e']
    gemm256<false, false, false><<<gE, blk512, 0, stream>>>(BC, BC + SD, Pp, D_, D_, S_, S_ / 4, 4, 2 * SD, 2 * SD, DD2);
    // 2b) Enorm[b] = sum_seg P  (in-place at P[4b])
    reduceN_bf16_inplace<<<2048, blk256, 0, stream>>>(Pp, 4, (B_ * D_ * D_) / 8);
    // 2c) convert Wd, Wa into dead P segs 1-2
    conv_bf16_w2<<<512, blk256, 0, stream>>>(Wd, Wa, Wdb, Wab, (D_ * D_) / 8);
    // 3) Ft[b][dout][e] = (Enorm[b] @ Wd^T)^T
    gemm_nt<false, true,  false><<<gF, blk256, 0, stream>>>(Enorm, Wdb, Ft, D_, D_, D_, D_, 1, 4 * DD2, 0, DD2);
    // 4) A[b][s][e] = relu(xb Wa^T) -> ws@0 (BC dead)
    gemm256<false, false, true ><<<gS, blk512, 0, stream>>>(xb, Wab, Ao, S_, D_, D_, D_, 1, SD, 0, SD);
    // 5) out = relu(A @ Ft-rows) f32 -> d_out (reads only ws; overwrites d_out)
    gemm256<true,  false, true ><<<gS, blk512, 0, stream>>>(Ao, Ft, (float*)d_out, S_, D_, D_, D_, 1, SD, DD2, SD);
}

// Round 13
// 240.707 us; speedup vs baseline: 2.0776x; 1.0055x over previous
//
#include <hip/hip_runtime.h>
#include <hip/hip_bf16.h>

#define D_ 1024
#define B_ 4
#define S_ 4096

typedef __attribute__((ext_vector_type(8))) short bf16x8;
typedef __attribute__((ext_vector_type(4))) float f32x4;
typedef __attribute__((ext_vector_type(4))) unsigned int u32x4;
typedef __attribute__((ext_vector_type(4))) unsigned short u16x4;

__device__ __forceinline__ unsigned short f2bf(float f) {
    unsigned int u = __builtin_bit_cast(unsigned int, f);
    u = u + 0x7fffu + ((u >> 16) & 1u);
    return (unsigned short)(u >> 16);
}
__device__ __forceinline__ unsigned int pk2(float a, float b) {
    return (unsigned int)f2bf(a) | ((unsigned int)f2bf(b) << 16);
}
__device__ __forceinline__ float bf2f(unsigned short h) {
    unsigned int u = ((unsigned int)h) << 16;
    return __builtin_bit_cast(float, u);
}
__device__ __forceinline__ void gload16(const void* g, void* l) {
    __builtin_amdgcn_global_load_lds(
        (const __attribute__((address_space(1))) void*)g,
        (__attribute__((address_space(3))) void*)l, 16, 0, 0);
}

// ---------------- elementwise helpers ----------------
__global__ __launch_bounds__(256)
void conv_bf16(const float* __restrict__ src, unsigned short* __restrict__ dst, int n8) {
    int i = blockIdx.x * blockDim.x + threadIdx.x;
    const int stride = gridDim.x * blockDim.x;
    for (; i < n8; i += stride) {
        f32x4 v0 = *(const f32x4*)(src + (size_t)i * 8);
        f32x4 v1 = *(const f32x4*)(src + (size_t)i * 8 + 4);
        u32x4 o;
        o[0] = pk2(v0[0], v0[1]);
        o[1] = pk2(v0[2], v0[3]);
        o[2] = pk2(v1[0], v1[1]);
        o[3] = pk2(v1[2], v1[3]);
        *(u32x4*)(dst + (size_t)i * 8) = o;
    }
}

__global__ __launch_bounds__(256)
void conv_bf16_w2(const float* __restrict__ s0, const float* __restrict__ s1,
                  unsigned short* __restrict__ d0, unsigned short* __restrict__ d1,
                  int n8_per) {
    int i = blockIdx.x * blockDim.x + threadIdx.x;
    const int stride = gridDim.x * blockDim.x;
    for (; i < 2 * n8_per; i += stride) {
        int w = i / n8_per;
        size_t j = (size_t)(i - w * n8_per) * 8;
        const float* s = w ? s1 : s0;
        unsigned short* d = w ? d1 : d0;
        f32x4 v0 = *(const f32x4*)(s + j);
        f32x4 v1 = *(const f32x4*)(s + j + 4);
        u32x4 o;
        o[0] = pk2(v0[0], v0[1]);
        o[1] = pk2(v0[2], v0[3]);
        o[2] = pk2(v1[0], v1[1]);
        o[3] = pk2(v1[2], v1[3]);
        *(u32x4*)(d + j) = o;
    }
}

// In-place segment reduce: E[b][i] = sum_seg P[b*split+seg][i], E stored at P[b*split].
__global__ __launch_bounds__(256)
void reduceN_bf16_inplace(unsigned short* __restrict__ P, int split, int n8_total) {
    int t = blockIdx.x * blockDim.x + threadIdx.x;
    const int stride = gridDim.x * blockDim.x;
    const int DD = D_ * D_;
    for (; t < n8_total; t += stride) {
        size_t idx = (size_t)t * 8;
        int b = (int)(idx / DD);
        size_t i = idx % DD;
        float s[8];
#pragma unroll
        for (int k = 0; k < 8; ++k) s[k] = 0.f;
        for (int seg = 0; seg < split; ++seg) {
            const unsigned short* p = P + (size_t)(b * split + seg) * DD + i;
            u16x4 v0 = *(const u16x4*)p;
            u16x4 v1 = *(const u16x4*)(p + 4);
#pragma unroll
            for (int k = 0; k < 4; ++k) { s[k] += bf2f(v0[k]); s[4 + k] += bf2f(v1[k]); }
        }
        u16x4 o0, o1;
#pragma unroll
        for (int k = 0; k < 4; ++k) { o0[k] = f2bf(s[k]); o1[k] = f2bf(s[4 + k]); }
        unsigned short* e = P + (size_t)(b * split) * DD + i;
        *(u16x4*)e = o0;
        *(u16x4*)(e + 4) = o1;
    }
}

// ---------------- 128x128 2-phase kernel (proven; small F-GEMM only) ----------------
#define BM 128
#define BN 128
#define BK 64
#define NTHR 256

template<bool OUT_F32, bool TRANS, bool RELU>
__global__ __launch_bounds__(NTHR)
void gemm_nt(const unsigned short* __restrict__ Ap, const unsigned short* __restrict__ Bp,
             void* __restrict__ Op, int M, int N, int K, int klen, int split,
             long long sA, long long sB, long long sO)
{
    __shared__ char lds_a[BM * BK * 2];
    __shared__ char lds_b[BN * BK * 2];

    const int tid   = threadIdx.x;
    const int bz    = blockIdx.z;
    const int batch = bz / split;
    const int k0    = (bz % split) * klen;
    const int bm    = blockIdx.y * BM;
    const int bn    = blockIdx.x * BN;

    const unsigned short* Abase = Ap + (size_t)batch * sA + (size_t)bm * K;
    const unsigned short* Bbase = Bp + (size_t)batch * sB + (size_t)bn * K;

    const int lane = tid & 63;
    const int wave = tid >> 6;
    const int wm   = (wave >> 1) * 64;
    const int wn   = (wave & 1) * 64;
    const int l16  = lane & 15;
    const int lhi  = lane >> 4;

    const int schnk = (lane & 7) ^ (lane >> 3);
    const char* gA0 = (const char*)(Abase + (size_t)(wave * 32 + (lane >> 3)) * K) + schnk * 16;
    const char* gB0 = (const char*)(Bbase + (size_t)(wave * 32 + (lane >> 3)) * K) + schnk * 16;
    char* lA0 = lds_a + wave * 4096;
    char* lB0 = lds_b + wave * 4096;

    f32x4 acc[4][4];
#pragma unroll
    for (int i = 0; i < 4; ++i)
#pragma unroll
        for (int j = 0; j < 4; ++j)
            acc[i][j] = (f32x4){0.f, 0.f, 0.f, 0.f};

    for (int kt = k0; kt < k0 + klen; kt += BK) {
#pragma unroll
        for (int p = 0; p < 4; ++p)
            gload16(gA0 + ((size_t)p * 8 * K + kt) * 2, lA0 + p * 1024);
#pragma unroll
        for (int p = 0; p < 4; ++p)
            gload16(gB0 + ((size_t)p * 8 * K + kt) * 2, lB0 + p * 1024);
        __syncthreads();
#pragma unroll
        for (int kk = 0; kk < BK / 32; ++kk) {
            bf16x8 af[4], bfr[4];
#pragma unroll
            for (int i = 0; i < 4; ++i) {
                int row = wm + i * 16 + l16;
                int byt = (row * 128 + kk * 64 + lhi * 16) ^ ((row & 7) << 4);
                af[i] = *(const bf16x8*)(lds_a + byt);
            }
#pragma unroll
            for (int j = 0; j < 4; ++j) {
                int row = wn + j * 16 + l16;
                int byt = (row * 128 + kk * 64 + lhi * 16) ^ ((row & 7) << 4);
                bfr[j] = *(const bf16x8*)(lds_b + byt);
            }
#pragma unroll
            for (int i = 0; i < 4; ++i)
#pragma unroll
                for (int j = 0; j < 4; ++j)
                    acc[i][j] = __builtin_amdgcn_mfma_f32_16x16x32_bf16(af[i], bfr[j], acc[i][j], 0, 0, 0);
        }
        __syncthreads();
    }

    const size_t obase = (size_t)bz * (size_t)sO;
    if constexpr (!TRANS) {
#pragma unroll
        for (int i = 0; i < 4; ++i) {
            const int m0 = bm + wm + i * 16 + lhi * 4;
#pragma unroll
            for (int j = 0; j < 4; ++j) {
                const int n = bn + wn + j * 16 + l16;
#pragma unroll
                for (int r = 0; r < 4; ++r) {
                    float v = acc[i][j][r];
                    if constexpr (RELU) v = fmaxf(v, 0.f);
                    size_t addr = obase + (size_t)(m0 + r) * N + n;
                    if constexpr (OUT_F32) ((float*)Op)[addr] = v;
                    else ((unsigned short*)Op)[addr] = f2bf(v);
                }
            }
        }
    } else {
#pragma unroll
        for (int i = 0; i < 4; ++i) {
            const int m0 = bm + wm + i * 16 + lhi * 4;
#pragma unroll
            for (int j = 0; j < 4; ++j) {
                const int n = bn + wn + j * 16 + l16;
                u16x4 h;
#pragma unroll
                for (int r = 0; r < 4; ++r) {
                    float v = acc[i][j][r];
                    if constexpr (RELU) v = fmaxf(v, 0.f);
                    h[r] = f2bf(v);
                }
                *(u16x4*)((unsigned short*)Op + obase + (size_t)n * M + m0) = h;
            }
        }
    }
}

// ---------------- 256x256 8-phase kernel, interleaved read-ahead (round 13) ----------------
// Same phase-granular schedule as r10/r12 (verified 242-243us, absmax 4096).
// Change: each 16-MFMA block split into halves (i4 0-1 / 2-3) with next-phase
// ds_reads issued BETWEEN halves, exploiting WAR liveness (mmA consumes a[0..1]
// only -> new a[0..1] readable after half 1; no extra register sets). Reads now
// start ~half-a-phase earlier and drain under mmB + barrier instead of stalling
// the next LGKM0. P3/P7 keep post-mm reads (reloaded b0 is consumed by all 16).
// Phase-level read/stage/vmcnt ordering identical to r12 -> hazard ledger holds.
#define CTILE 65536
#define CBOFF 32768

template<bool OUT_F32, bool TRANS, bool RELU>
__global__ __launch_bounds__(512, 2)
void gemm256(const unsigned short* __restrict__ Ap, const unsigned short* __restrict__ Bp,
             void* __restrict__ Op, int M, int N, int K, int klen, int split,
             long long sA, long long sB, long long sO)
{
    __shared__ char lds[131072];
    const int tid  = threadIdx.x;
    const int wave = tid >> 6;
    const int lane = tid & 63;

    // XCD-aware bijective block swizzle (all grids have nwg % 8 == 0)
    const int gx = gridDim.x, gy = gridDim.y;
    const int f   = blockIdx.x + gx * (blockIdx.y + gy * blockIdx.z);
    const int nwg = gx * gy * (int)gridDim.z;
    const int s   = (f & 7) * (nwg >> 3) + (f >> 3);
    const int lx  = s % gx;
    const int lyz = s / gx;
    const int ly  = lyz % gy;
    const int lz  = lyz / gy;

    const int batch = lz / split;
    const int k0    = (lz % split) * klen;
    const int bm    = ly * 256;
    const int bn    = lx * 256;

    const int wm  = (wave >> 2) * 128;
    const int wn  = (wave & 3) * 64;
    const int l16 = lane & 15, lhi = lane >> 4;

    const unsigned short* Abase = Ap + (size_t)batch * sA + (size_t)bm * K;
    const unsigned short* Bbase = Bp + (size_t)batch * sB + (size_t)bn * K;
    const int srow  = lane >> 3;
    const int schnk = (lane & 7) ^ srow;
    const size_t K2 = (size_t)K * 2;
    const char* gA = (const char*)Abase + (size_t)srow * K2 + (size_t)schnk * 16 + (size_t)k0 * 2;
    const char* gB = (const char*)Bbase + (size_t)srow * K2 + (size_t)schnk * 16 + (size_t)k0 * 2;

    // lane-constant LDS read bases; kk*64 folded INSIDE the XOR (r12-verified)
    const int lxor = (l16 & 7) << 4;
    const int aX = (wm + l16) * 128 + lhi * 16;
    const int bX = (wn + l16) * 128 + lhi * 16;
    const char* aB00 = lds + 0 * CTILE + ((aX + 0 * 64) ^ lxor);
    const char* aB01 = lds + 0 * CTILE + ((aX + 1 * 64) ^ lxor);
    const char* aB10 = lds + 1 * CTILE + ((aX + 0 * 64) ^ lxor);
    const char* aB11 = lds + 1 * CTILE + ((aX + 1 * 64) ^ lxor);
    const char* bB00 = lds + 0 * CTILE + CBOFF + ((bX + 0 * 64) ^ lxor);
    const char* bB01 = lds + 0 * CTILE + CBOFF + ((bX + 1 * 64) ^ lxor);
    const char* bB10 = lds + 1 * CTILE + CBOFF + ((bX + 0 * 64) ^ lxor);
    const char* bB11 = lds + 1 * CTILE + CBOFF + ((bX + 1 * 64) ^ lxor);

    f32x4 acc[8][4];
#pragma unroll
    for (int i = 0; i < 8; ++i)
#pragma unroll
        for (int j = 0; j < 4; ++j)
            acc[i][j] = (f32x4){0.f, 0.f, 0.f, 0.f};

    bf16x8 a[4][2], b0[2][2], b1[2][2];

    auto stageA2 = [&](int c, int t, int h) {
#pragma unroll
        for (int p = 0; p < 2; ++p)
            gload16(gA + (size_t)t * 128 + (size_t)(h * 128 + wave * 16 + p * 8) * K2,
                    lds + c * CTILE + h * 16384 + wave * 2048 + p * 1024);
    };
    auto stageB2 = [&](int c, int t, int h) {
#pragma unroll
        for (int p = 0; p < 2; ++p)
            gload16(gB + (size_t)t * 128 + (size_t)(h * 128 + wave * 16 + p * 8) * K2,
                    lds + c * CTILE + CBOFF + h * 16384 + wave * 2048 + p * 1024);
    };
    // A-fragment reads, half granularity (i4 range [lo,lo+2))
    auto ldAh = [&](int c, int mh, int lo) {
        const char* base0 = c ? aB10 : aB00;
        const char* base1 = c ? aB11 : aB01;
#pragma unroll
        for (int i4 = 0; i4 < 2; ++i4) {
            const int imm = (mh * 64 + (lo + i4) * 16) * 128;   // multiple of 2048
            a[lo + i4][0] = *(const bf16x8*)(base0 + imm);
            a[lo + i4][1] = *(const bf16x8*)(base1 + imm);
        }
    };
    auto ldBh = [&](int c, int nh, bf16x8 (&bb)[2][2], int j2) {
        const char* base0 = c ? bB10 : bB00;
        const char* base1 = c ? bB11 : bB01;
        const int imm = (nh * 32 + j2 * 16) * 128;              // multiple of 2048
        bb[j2][0] = *(const bf16x8*)(base0 + imm);
        bb[j2][1] = *(const bf16x8*)(base1 + imm);
    };
    auto ldB = [&](int c, int nh, bf16x8 (&bb)[2][2]) {
        ldBh(c, nh, bb, 0); ldBh(c, nh, bb, 1);
    };
    // MFMA halves: mmH(lo) covers i4 in [lo, lo+2)
    auto mmH = [&](int mh, int nh, bf16x8 (&bb)[2][2], int lo) {
        __builtin_amdgcn_s_setprio(1);
#pragma unroll
        for (int i4 = 0; i4 < 2; ++i4)
#pragma unroll
            for (int j2 = 0; j2 < 2; ++j2)
#pragma unroll
                for (int kk = 0; kk < 2; ++kk)
                    acc[mh * 4 + lo + i4][nh * 2 + j2] = __builtin_amdgcn_mfma_f32_16x16x32_bf16(
                        a[lo + i4][kk], bb[j2][kk], acc[mh * 4 + lo + i4][nh * 2 + j2], 0, 0, 0);
        __builtin_amdgcn_s_setprio(0);
    };
    auto mm = [&](int mh, int nh, bf16x8 (&bb)[2][2]) { mmH(mh, nh, bb, 0); mmH(mh, nh, bb, 2); };

#define BAR()   __builtin_amdgcn_s_barrier()
#define LGKM0() asm volatile("s_waitcnt lgkmcnt(0)" ::: "memory")
#define VM2()   asm volatile("s_waitcnt vmcnt(2)" ::: "memory")
#define VM4()   asm volatile("s_waitcnt vmcnt(4)" ::: "memory")
#define VM6()   asm volatile("s_waitcnt vmcnt(6)" ::: "memory")

    const int NT = klen / 64;
    // prologue: buf0 full (8), buf1 B full + A half0 (6); A1(t=1)[1] staged at P1.
    stageB2(0, 0, 0); stageB2(0, 0, 1); stageA2(0, 0, 0); stageA2(0, 0, 1);
    stageB2(1, 1, 0); stageB2(1, 1, 1); stageA2(1, 1, 0);
    VM6();
    BAR();
    ldB(0, 0, b0); ldAh(0, 0, 0); ldAh(0, 0, 2);

    for (int itr = 0; itr < NT / 2; ++itr) {
        const int t1  = 2 * itr + 1;
        const int tp0 = (2 * itr + 2) % NT;
        const int tp1 = (2 * itr + 3) % NT;
        // P1: mm(0,0,b0) halves; ldB(0,1,b1) interleaved (b1 free)
        LGKM0(); mmH(0, 0, b0, 0);
        ldBh(0, 1, b1, 0);
        mmH(0, 0, b0, 2);
        ldBh(0, 1, b1, 1); stageA2(1, t1, 1);
        BAR();
        // P2: mm(0,1,b1); ldA(0,1) interleaved via WAR-halves on a
        LGKM0(); mmH(0, 1, b1, 0);
        ldAh(0, 1, 0);
        mmH(0, 1, b1, 2);
        ldAh(0, 1, 2); VM4();
        BAR();
        // P3: mm(1,0,b0) full (reload of b0 conflicts whole mm)
        LGKM0(); mm(1, 0, b0);
        ldB(1, 0, b0); stageB2(0, tp0, 0); VM2();
        BAR();
        // P4: mm(1,1,b1); ldA(1,0) interleaved
        LGKM0(); mmH(1, 1, b1, 0);
        ldAh(1, 0, 0);
        mmH(1, 1, b1, 2);
        ldAh(1, 0, 2); stageB2(0, tp0, 1); stageA2(0, tp0, 0);
        BAR();
        // P5: mm(0,0,b0); ldB(1,1,b1) interleaved
        LGKM0(); mmH(0, 0, b0, 0);
        ldBh(1, 1, b1, 0);
        mmH(0, 0, b0, 2);
        ldBh(1, 1, b1, 1); stageA2(0, tp0, 1);
        BAR();
        // P6: mm(0,1,b1); ldA(1,1) interleaved
        LGKM0(); mmH(0, 1, b1, 0);
        ldAh(1, 1, 0);
        mmH(0, 1, b1, 2);
        ldAh(1, 1, 2); VM4();
        BAR();
        // P7: mm(1,0,b0) full
        LGKM0(); mm(1, 0, b0);
        ldB(0, 0, b0); stageB2(1, tp1, 0); VM2();
        BAR();
        // P8: mm(1,1,b1); ldA(0,0) interleaved
        LGKM0(); mmH(1, 1, b1, 0);
        ldAh(0, 0, 0);
        mmH(1, 1, b1, 2);
        ldAh(0, 0, 2); stageB2(1, tp1, 1); stageA2(1, tp1, 0);
        BAR();
    }
    asm volatile("s_waitcnt vmcnt(0)" ::: "memory");

    const size_t obase = (size_t)lz * (size_t)sO;
    if constexpr (!TRANS) {
#pragma unroll
        for (int i = 0; i < 8; ++i) {
            const int m0 = bm + wm + i * 16 + lhi * 4;
#pragma unroll
            for (int j = 0; j < 4; ++j) {
                const int n = bn + wn + j * 16 + l16;
#pragma unroll
                for (int r = 0; r < 4; ++r) {
                    float v = acc[i][j][r];
                    if constexpr (RELU) v = fmaxf(v, 0.f);
                    size_t addr = obase + (size_t)(m0 + r) * N + n;
                    if constexpr (OUT_F32) ((float*)Op)[addr] = v;
                    else ((unsigned short*)Op)[addr] = f2bf(v);
                }
            }
        }
    } else {
#pragma unroll
        for (int i = 0; i < 8; ++i) {
            const int m0 = bm + wm + i * 16 + lhi * 4;
#pragma unroll
            for (int j = 0; j < 4; ++j) {
                const int n = bn + wn + j * 16 + l16;
                u16x4 h;
#pragma unroll
                for (int r = 0; r < 4; ++r) {
                    float v = acc[i][j][r];
                    if constexpr (RELU) v = fmaxf(v, 0.f);
                    h[r] = f2bf(v);
                }
                *(u16x4*)((unsigned short*)Op + obase + (size_t)n * M + m0) = h;
            }
        }
    }
#undef BAR
#undef LGKM0
#undef VM2
#undef VM4
#undef VM6
}

extern "C" void kernel_launch(void* const* d_in, const int* in_sizes, int n_in,
                              void* d_out, int out_size, void* d_ws, size_t ws_size,
                              hipStream_t stream) {
    (void)in_sizes; (void)n_in; (void)out_size; (void)ws_size;
    const float* x  = (const float*)d_in[0];
    const float* Wa = (const float*)d_in[1];
    const float* Wb = (const float*)d_in[2];
    const float* Wc = (const float*)d_in[3];
    const float* Wd = (const float*)d_in[4];

    const long long SD  = (long long)S_ * D_;
    const long long DD2 = (long long)D_ * D_;
    const size_t MB = 1024 * 1024;

    // ws (64MB): fused BC output [b][2048][S] bf16 = 64MB exactly.
    //   After E: BC dead -> A @0-32MB, Ft @32-40MB.
    unsigned short* BC = (unsigned short*)d_ws;
    unsigned short* Ao = (unsigned short*)d_ws;
    unsigned short* Ft = (unsigned short*)((char*)d_ws + 32 * MB);
    // d_out scratch (64MB): xb@0-32 | P (16 segs x 2MB) @32-64.
    //   Wbb@56,Wcb@58 die after projBC (overwritten by P segs 12-15).
    //   After reduce: Enorm[b] in-place at P[4b]; dead segs 1-2 -> Wdb@34, Wab@36.
    char* ob = (char*)d_out;
    unsigned short* xb    = (unsigned short*)ob;
    unsigned short* Pp    = (unsigned short*)(ob + 32 * MB);
    unsigned short* Enorm = Pp;                              // batch stride 4*DD2
    unsigned short* Wdb   = (unsigned short*)(ob + 34 * MB);
    unsigned short* Wab   = (unsigned short*)(ob + 36 * MB);
    unsigned short* Wbb   = (unsigned short*)(ob + 56 * MB); // Wbb|Wcb contiguous
    unsigned short* Wcb   = (unsigned short*)(ob + 58 * MB);

    dim3 blk256(256, 1, 1);
    dim3 blk512(512, 1, 1);
    dim3 gBC(2048 / 256, S_ / 256, B_);        // (8,16,4) = 512
    dim3 gE(D_ / 256, D_ / 256, B_ * 4);       // (4,4,16) = 256, split-K=4
    dim3 gS(D_ / 256, S_ / 256, B_);           // (4,16,4) = 256
    dim3 gF(D_ / BN, D_ / BM, B_);             // (8,8,4)

    // 0) convert x and Wb|Wc
    conv_bf16<<<2048, blk256, 0, stream>>>(x, xb, (B_ * S_ * D_) / 8);
    conv_bf16_w2<<<512, blk256, 0, stream>>>(Wb, Wc, Wbb, Wcb, (D_ * D_) / 8);
    // 1) fused projections: BC[b][n][s] = relu(xb [Wb;Wc]^T)^T, n in [0,2048)
    gemm256<false, true,  true ><<<gBC, blk512, 0, stream>>>(xb, Wbb, BC, S_, 2048, D_, D_, 1, SD, 0, 2 * SD);
    // 2) E partials: P[b*4+seg] = sum_{s in seg} Bm[s,e] C[s,e']
    gemm256<false, false, false><<<gE, blk512, 0, stream>>>(BC, BC + SD, Pp, D_, D_, S_, S_ / 4, 4, 2 * SD, 2 * SD, DD2);
    // 2b) Enorm[b] = sum_seg P  (in-place at P[4b])
    reduceN_bf16_inplace<<<2048, blk256, 0, stream>>>(Pp, 4, (B_ * D_ * D_) / 8);
    // 2c) convert Wd, Wa into dead P segs 1-2
    conv_bf16_w2<<<512, blk256, 0, stream>>>(Wd, Wa, Wdb, Wab, (D_ * D_) / 8);
    // 3) Ft[b][dout][e] = (Enorm[b] @ Wd^T)^T
    gemm_nt<false, true,  false><<<gF, blk256, 0, stream>>>(Enorm, Wdb, Ft, D_, D_, D_, D_, 1, 4 * DD2, 0, DD2);
    // 4) A[b][s][e] = relu(xb Wa^T) -> ws@0 (BC dead)
    gemm256<false, false, true ><<<gS, blk512, 0, stream>>>(xb, Wab, Ao, S_, D_, D_, D_, 1, SD, 0, SD);
    // 5) out = relu(A @ Ft-rows) f32 -> d_out (reads only ws; overwrites d_out)
    gemm256<true,  false, true ><<<gS, blk512, 0, stream>>>(Ao, Ft, (float*)d_out, S_, D_, D_, D_, 1, SD, DD2, SD);
}

// Round 14
// 237.188 us; speedup vs baseline: 2.1084x; 1.0148x over previous
//
#include <hip/hip_runtime.h>
#include <hip/hip_bf16.h>

#define D_ 1024
#define B_ 4
#define S_ 4096

typedef __attribute__((ext_vector_type(8))) short bf16x8;
typedef __attribute__((ext_vector_type(4))) float f32x4;
typedef __attribute__((ext_vector_type(4))) unsigned int u32x4;
typedef __attribute__((ext_vector_type(4))) unsigned short u16x4;

__device__ __forceinline__ unsigned short f2bf(float f) {
    unsigned int u = __builtin_bit_cast(unsigned int, f);
    u = u + 0x7fffu + ((u >> 16) & 1u);
    return (unsigned short)(u >> 16);
}
__device__ __forceinline__ unsigned int pk2(float a, float b) {
    return (unsigned int)f2bf(a) | ((unsigned int)f2bf(b) << 16);
}
__device__ __forceinline__ float bf2f(unsigned short h) {
    unsigned int u = ((unsigned int)h) << 16;
    return __builtin_bit_cast(float, u);
}
__device__ __forceinline__ void gload16(const void* g, void* l) {
    __builtin_amdgcn_global_load_lds(
        (const __attribute__((address_space(1))) void*)g,
        (__attribute__((address_space(3))) void*)l, 16, 0, 0);
}

// ---------------- fused elementwise helpers ----------------
__device__ __forceinline__ void conv8(const float* s, unsigned short* d, size_t j) {
    f32x4 v0 = *(const f32x4*)(s + j);
    f32x4 v1 = *(const f32x4*)(s + j + 4);
    u32x4 o;
    o[0] = pk2(v0[0], v0[1]);
    o[1] = pk2(v0[2], v0[3]);
    o[2] = pk2(v1[0], v1[1]);
    o[3] = pk2(v1[2], v1[3]);
    *(u32x4*)(d + j) = o;
}

// x + Wb + Wc -> bf16 in ONE launch (wave-uniform branch boundaries)
__global__ __launch_bounds__(256)
void conv_all(const float* __restrict__ x, const float* __restrict__ Wb,
              const float* __restrict__ Wc,
              unsigned short* __restrict__ xb, unsigned short* __restrict__ wbb,
              unsigned short* __restrict__ wcb, int n8x, int n8w) {
    int i = blockIdx.x * blockDim.x + threadIdx.x;
    const int stride = gridDim.x * blockDim.x;
    const int ntot = n8x + 2 * n8w;
    for (; i < ntot; i += stride) {
        if (i < n8x)                conv8(x,  xb,  (size_t)i * 8);
        else if (i < n8x + n8w)     conv8(Wb, wbb, (size_t)(i - n8x) * 8);
        else                        conv8(Wc, wcb, (size_t)(i - n8x - n8w) * 8);
    }
}

// P-segment reduce (E[b][i] = sum_seg P[b*4+seg][i], contiguous output)
// fused with Wd/Wa conversion, ONE launch.
__global__ __launch_bounds__(256)
void reduce_convw(const unsigned short* __restrict__ P, unsigned short* __restrict__ E,
                  const float* __restrict__ Wd, const float* __restrict__ Wa,
                  unsigned short* __restrict__ wdb, unsigned short* __restrict__ wab,
                  int n8e, int n8w) {
    int t = blockIdx.x * blockDim.x + threadIdx.x;
    const int stride = gridDim.x * blockDim.x;
    const int DD = D_ * D_;
    const int ntot = n8e + 2 * n8w;
    for (; t < ntot; t += stride) {
        if (t < n8e) {
            size_t idx = (size_t)t * 8;
            int b = (int)(idx / DD);
            size_t i = idx % DD;
            float s[8];
#pragma unroll
            for (int k = 0; k < 8; ++k) s[k] = 0.f;
#pragma unroll
            for (int seg = 0; seg < 4; ++seg) {
                const unsigned short* p = P + (size_t)(b * 4 + seg) * DD + i;
                u16x4 v0 = *(const u16x4*)p;
                u16x4 v1 = *(const u16x4*)(p + 4);
#pragma unroll
                for (int k = 0; k < 4; ++k) { s[k] += bf2f(v0[k]); s[4 + k] += bf2f(v1[k]); }
            }
            u16x4 o0, o1;
#pragma unroll
            for (int k = 0; k < 4; ++k) { o0[k] = f2bf(s[k]); o1[k] = f2bf(s[4 + k]); }
            *(u16x4*)(E + idx) = o0;
            *(u16x4*)(E + idx + 4) = o1;
        } else if (t < n8e + n8w) {
            conv8(Wd, wdb, (size_t)(t - n8e) * 8);
        } else {
            conv8(Wa, wab, (size_t)(t - n8e - n8w) * 8);
        }
    }
}

// ---------------- 128x128 2-phase kernel (proven; small F-GEMM only) ----------------
#define BM 128
#define BN 128
#define BK 64
#define NTHR 256

template<bool OUT_F32, bool TRANS, bool RELU>
__global__ __launch_bounds__(NTHR)
void gemm_nt(const unsigned short* __restrict__ Ap, const unsigned short* __restrict__ Bp,
             void* __restrict__ Op, int M, int N, int K, int klen, int split,
             long long sA, long long sB, long long sO)
{
    __shared__ char lds_a[BM * BK * 2];
    __shared__ char lds_b[BN * BK * 2];

    const int tid   = threadIdx.x;
    const int bz    = blockIdx.z;
    const int batch = bz / split;
    const int k0    = (bz % split) * klen;
    const int bm    = blockIdx.y * BM;
    const int bn    = blockIdx.x * BN;

    const unsigned short* Abase = Ap + (size_t)batch * sA + (size_t)bm * K;
    const unsigned short* Bbase = Bp + (size_t)batch * sB + (size_t)bn * K;

    const int lane = tid & 63;
    const int wave = tid >> 6;
    const int wm   = (wave >> 1) * 64;
    const int wn   = (wave & 1) * 64;
    const int l16  = lane & 15;
    const int lhi  = lane >> 4;

    const int schnk = (lane & 7) ^ (lane >> 3);
    const char* gA0 = (const char*)(Abase + (size_t)(wave * 32 + (lane >> 3)) * K) + schnk * 16;
    const char* gB0 = (const char*)(Bbase + (size_t)(wave * 32 + (lane >> 3)) * K) + schnk * 16;
    char* lA0 = lds_a + wave * 4096;
    char* lB0 = lds_b + wave * 4096;

    f32x4 acc[4][4];
#pragma unroll
    for (int i = 0; i < 4; ++i)
#pragma unroll
        for (int j = 0; j < 4; ++j)
            acc[i][j] = (f32x4){0.f, 0.f, 0.f, 0.f};

    for (int kt = k0; kt < k0 + klen; kt += BK) {
#pragma unroll
        for (int p = 0; p < 4; ++p)
            gload16(gA0 + ((size_t)p * 8 * K + kt) * 2, lA0 + p * 1024);
#pragma unroll
        for (int p = 0; p < 4; ++p)
            gload16(gB0 + ((size_t)p * 8 * K + kt) * 2, lB0 + p * 1024);
        __syncthreads();
#pragma unroll
        for (int kk = 0; kk < BK / 32; ++kk) {
            bf16x8 af[4], bfr[4];
#pragma unroll
            for (int i = 0; i < 4; ++i) {
                int row = wm + i * 16 + l16;
                int byt = (row * 128 + kk * 64 + lhi * 16) ^ ((row & 7) << 4);
                af[i] = *(const bf16x8*)(lds_a + byt);
            }
#pragma unroll
            for (int j = 0; j < 4; ++j) {
                int row = wn + j * 16 + l16;
                int byt = (row * 128 + kk * 64 + lhi * 16) ^ ((row & 7) << 4);
                bfr[j] = *(const bf16x8*)(lds_b + byt);
            }
#pragma unroll
            for (int i = 0; i < 4; ++i)
#pragma unroll
                for (int j = 0; j < 4; ++j)
                    acc[i][j] = __builtin_amdgcn_mfma_f32_16x16x32_bf16(af[i], bfr[j], acc[i][j], 0, 0, 0);
        }
        __syncthreads();
    }

    const size_t obase = (size_t)bz * (size_t)sO;
    if constexpr (!TRANS) {
#pragma unroll
        for (int i = 0; i < 4; ++i) {
            const int m0 = bm + wm + i * 16 + lhi * 4;
#pragma unroll
            for (int j = 0; j < 4; ++j) {
                const int n = bn + wn + j * 16 + l16;
#pragma unroll
                for (int r = 0; r < 4; ++r) {
                    float v = acc[i][j][r];
                    if constexpr (RELU) v = fmaxf(v, 0.f);
                    size_t addr = obase + (size_t)(m0 + r) * N + n;
                    if constexpr (OUT_F32) ((float*)Op)[addr] = v;
                    else ((unsigned short*)Op)[addr] = f2bf(v);
                }
            }
        }
    } else {
#pragma unroll
        for (int i = 0; i < 4; ++i) {
            const int m0 = bm + wm + i * 16 + lhi * 4;
#pragma unroll
            for (int j = 0; j < 4; ++j) {
                const int n = bn + wn + j * 16 + l16;
                u16x4 h;
#pragma unroll
                for (int r = 0; r < 4; ++r) {
                    float v = acc[i][j][r];
                    if constexpr (RELU) v = fmaxf(v, 0.f);
                    h[r] = f2bf(v);
                }
                *(u16x4*)((unsigned short*)Op + obase + (size_t)n * M + m0) = h;
            }
        }
    }
}

// ---------------- 256x256 8-phase kernel (FROZEN, r13-verified 240.7us) ----------------
#define CTILE 65536
#define CBOFF 32768

template<bool OUT_F32, bool TRANS, bool RELU>
__global__ __launch_bounds__(512, 2)
void gemm256(const unsigned short* __restrict__ Ap, const unsigned short* __restrict__ Bp,
             void* __restrict__ Op, int M, int N, int K, int klen, int split,
             long long sA, long long sB, long long sO)
{
    __shared__ char lds[131072];
    const int tid  = threadIdx.x;
    const int wave = tid >> 6;
    const int lane = tid & 63;

    // XCD-aware bijective block swizzle (all grids have nwg % 8 == 0)
    const int gx = gridDim.x, gy = gridDim.y;
    const int f   = blockIdx.x + gx * (blockIdx.y + gy * blockIdx.z);
    const int nwg = gx * gy * (int)gridDim.z;
    const int s   = (f & 7) * (nwg >> 3) + (f >> 3);
    const int lx  = s % gx;
    const int lyz = s / gx;
    const int ly  = lyz % gy;
    const int lz  = lyz / gy;

    const int batch = lz / split;
    const int k0    = (lz % split) * klen;
    const int bm    = ly * 256;
    const int bn    = lx * 256;

    const int wm  = (wave >> 2) * 128;
    const int wn  = (wave & 3) * 64;
    const int l16 = lane & 15, lhi = lane >> 4;

    const unsigned short* Abase = Ap + (size_t)batch * sA + (size_t)bm * K;
    const unsigned short* Bbase = Bp + (size_t)batch * sB + (size_t)bn * K;
    const int srow  = lane >> 3;
    const int schnk = (lane & 7) ^ srow;
    const size_t K2 = (size_t)K * 2;
    const char* gA = (const char*)Abase + (size_t)srow * K2 + (size_t)schnk * 16 + (size_t)k0 * 2;
    const char* gB = (const char*)Bbase + (size_t)srow * K2 + (size_t)schnk * 16 + (size_t)k0 * 2;

    // lane-constant LDS read bases; kk*64 folded INSIDE the XOR (r12-verified)
    const int lxor = (l16 & 7) << 4;
    const int aX = (wm + l16) * 128 + lhi * 16;
    const int bX = (wn + l16) * 128 + lhi * 16;
    const char* aB00 = lds + 0 * CTILE + ((aX + 0 * 64) ^ lxor);
    const char* aB01 = lds + 0 * CTILE + ((aX + 1 * 64) ^ lxor);
    const char* aB10 = lds + 1 * CTILE + ((aX + 0 * 64) ^ lxor);
    const char* aB11 = lds + 1 * CTILE + ((aX + 1 * 64) ^ lxor);
    const char* bB00 = lds + 0 * CTILE + CBOFF + ((bX + 0 * 64) ^ lxor);
    const char* bB01 = lds + 0 * CTILE + CBOFF + ((bX + 1 * 64) ^ lxor);
    const char* bB10 = lds + 1 * CTILE + CBOFF + ((bX + 0 * 64) ^ lxor);
    const char* bB11 = lds + 1 * CTILE + CBOFF + ((bX + 1 * 64) ^ lxor);

    f32x4 acc[8][4];
#pragma unroll
    for (int i = 0; i < 8; ++i)
#pragma unroll
        for (int j = 0; j < 4; ++j)
            acc[i][j] = (f32x4){0.f, 0.f, 0.f, 0.f};

    bf16x8 a[4][2], b0[2][2], b1[2][2];

    auto stageA2 = [&](int c, int t, int h) {
#pragma unroll
        for (int p = 0; p < 2; ++p)
            gload16(gA + (size_t)t * 128 + (size_t)(h * 128 + wave * 16 + p * 8) * K2,
                    lds + c * CTILE + h * 16384 + wave * 2048 + p * 1024);
    };
    auto stageB2 = [&](int c, int t, int h) {
#pragma unroll
        for (int p = 0; p < 2; ++p)
            gload16(gB + (size_t)t * 128 + (size_t)(h * 128 + wave * 16 + p * 8) * K2,
                    lds + c * CTILE + CBOFF + h * 16384 + wave * 2048 + p * 1024);
    };
    auto ldAh = [&](int c, int mh, int lo) {
        const char* base0 = c ? aB10 : aB00;
        const char* base1 = c ? aB11 : aB01;
#pragma unroll
        for (int i4 = 0; i4 < 2; ++i4) {
            const int imm = (mh * 64 + (lo + i4) * 16) * 128;   // multiple of 2048
            a[lo + i4][0] = *(const bf16x8*)(base0 + imm);
            a[lo + i4][1] = *(const bf16x8*)(base1 + imm);
        }
    };
    auto ldBh = [&](int c, int nh, bf16x8 (&bb)[2][2], int j2) {
        const char* base0 = c ? bB10 : bB00;
        const char* base1 = c ? bB11 : bB01;
        const int imm = (nh * 32 + j2 * 16) * 128;              // multiple of 2048
        bb[j2][0] = *(const bf16x8*)(base0 + imm);
        bb[j2][1] = *(const bf16x8*)(base1 + imm);
    };
    auto ldB = [&](int c, int nh, bf16x8 (&bb)[2][2]) {
        ldBh(c, nh, bb, 0); ldBh(c, nh, bb, 1);
    };
    auto mmH = [&](int mh, int nh, bf16x8 (&bb)[2][2], int lo) {
        __builtin_amdgcn_s_setprio(1);
#pragma unroll
        for (int i4 = 0; i4 < 2; ++i4)
#pragma unroll
            for (int j2 = 0; j2 < 2; ++j2)
#pragma unroll
                for (int kk = 0; kk < 2; ++kk)
                    acc[mh * 4 + lo + i4][nh * 2 + j2] = __builtin_amdgcn_mfma_f32_16x16x32_bf16(
                        a[lo + i4][kk], bb[j2][kk], acc[mh * 4 + lo + i4][nh * 2 + j2], 0, 0, 0);
        __builtin_amdgcn_s_setprio(0);
    };
    auto mm = [&](int mh, int nh, bf16x8 (&bb)[2][2]) { mmH(mh, nh, bb, 0); mmH(mh, nh, bb, 2); };

#define BAR()   __builtin_amdgcn_s_barrier()
#define LGKM0() asm volatile("s_waitcnt lgkmcnt(0)" ::: "memory")
#define VM2()   asm volatile("s_waitcnt vmcnt(2)" ::: "memory")
#define VM4()   asm volatile("s_waitcnt vmcnt(4)" ::: "memory")
#define VM6()   asm volatile("s_waitcnt vmcnt(6)" ::: "memory")

    const int NT = klen / 64;
    stageB2(0, 0, 0); stageB2(0, 0, 1); stageA2(0, 0, 0); stageA2(0, 0, 1);
    stageB2(1, 1, 0); stageB2(1, 1, 1); stageA2(1, 1, 0);
    VM6();
    BAR();
    ldB(0, 0, b0); ldAh(0, 0, 0); ldAh(0, 0, 2);

    for (int itr = 0; itr < NT / 2; ++itr) {
        const int t1  = 2 * itr + 1;
        const int tp0 = (2 * itr + 2) % NT;
        const int tp1 = (2 * itr + 3) % NT;
        // P1
        LGKM0(); mmH(0, 0, b0, 0);
        ldBh(0, 1, b1, 0);
        mmH(0, 0, b0, 2);
        ldBh(0, 1, b1, 1); stageA2(1, t1, 1);
        BAR();
        // P2
        LGKM0(); mmH(0, 1, b1, 0);
        ldAh(0, 1, 0);
        mmH(0, 1, b1, 2);
        ldAh(0, 1, 2); VM4();
        BAR();
        // P3
        LGKM0(); mm(1, 0, b0);
        ldB(1, 0, b0); stageB2(0, tp0, 0); VM2();
        BAR();
        // P4
        LGKM0(); mmH(1, 1, b1, 0);
        ldAh(1, 0, 0);
        mmH(1, 1, b1, 2);
        ldAh(1, 0, 2); stageB2(0, tp0, 1); stageA2(0, tp0, 0);
        BAR();
        // P5
        LGKM0(); mmH(0, 0, b0, 0);
        ldBh(1, 1, b1, 0);
        mmH(0, 0, b0, 2);
        ldBh(1, 1, b1, 1); stageA2(0, tp0, 1);
        BAR();
        // P6
        LGKM0(); mmH(0, 1, b1, 0);
        ldAh(1, 1, 0);
        mmH(0, 1, b1, 2);
        ldAh(1, 1, 2); VM4();
        BAR();
        // P7
        LGKM0(); mm(1, 0, b0);
        ldB(0, 0, b0); stageB2(1, tp1, 0); VM2();
        BAR();
        // P8
        LGKM0(); mmH(1, 1, b1, 0);
        ldAh(0, 0, 0);
        mmH(1, 1, b1, 2);
        ldAh(0, 0, 2); stageB2(1, tp1, 1); stageA2(1, tp1, 0);
        BAR();
    }
    asm volatile("s_waitcnt vmcnt(0)" ::: "memory");

    const size_t obase = (size_t)lz * (size_t)sO;
    if constexpr (!TRANS) {
#pragma unroll
        for (int i = 0; i < 8; ++i) {
            const int m0 = bm + wm + i * 16 + lhi * 4;
#pragma unroll
            for (int j = 0; j < 4; ++j) {
                const int n = bn + wn + j * 16 + l16;
#pragma unroll
                for (int r = 0; r < 4; ++r) {
                    float v = acc[i][j][r];
                    if constexpr (RELU) v = fmaxf(v, 0.f);
                    size_t addr = obase + (size_t)(m0 + r) * N + n;
                    if constexpr (OUT_F32) ((float*)Op)[addr] = v;
                    else ((unsigned short*)Op)[addr] = f2bf(v);
                }
            }
        }
    } else {
#pragma unroll
        for (int i = 0; i < 8; ++i) {
            const int m0 = bm + wm + i * 16 + lhi * 4;
#pragma unroll
            for (int j = 0; j < 4; ++j) {
                const int n = bn + wn + j * 16 + l16;
                u16x4 h;
#pragma unroll
                for (int r = 0; r < 4; ++r) {
                    float v = acc[i][j][r];
                    if constexpr (RELU) v = fmaxf(v, 0.f);
                    h[r] = f2bf(v);
                }
                *(u16x4*)((unsigned short*)Op + obase + (size_t)n * M + m0) = h;
            }
        }
    }
#undef BAR
#undef LGKM0
#undef VM2
#undef VM4
#undef VM6
}

extern "C" void kernel_launch(void* const* d_in, const int* in_sizes, int n_in,
                              void* d_out, int out_size, void* d_ws, size_t ws_size,
                              hipStream_t stream) {
    (void)in_sizes; (void)n_in; (void)out_size; (void)ws_size;
    const float* x  = (const float*)d_in[0];
    const float* Wa = (const float*)d_in[1];
    const float* Wb = (const float*)d_in[2];
    const float* Wc = (const float*)d_in[3];
    const float* Wd = (const float*)d_in[4];

    const long long SD  = (long long)S_ * D_;
    const long long DD2 = (long long)D_ * D_;
    const size_t MB = 1024 * 1024;

    // ws (64MB): BC @0-64 (dies after E). Then: Enorm @0-8 | Ft @32-40 |
    //   Wdb @40-42 | Wab @42-44 | Ao @0-32 (overwrites dead Enorm after F).
    unsigned short* BC    = (unsigned short*)d_ws;
    unsigned short* Enorm = (unsigned short*)d_ws;                        // 8MB
    unsigned short* Ao    = (unsigned short*)d_ws;                        // 32MB
    unsigned short* Ft    = (unsigned short*)((char*)d_ws + 32 * MB);     // 8MB
    unsigned short* Wdb   = (unsigned short*)((char*)d_ws + 40 * MB);
    unsigned short* Wab   = (unsigned short*)((char*)d_ws + 42 * MB);
    // d_out scratch (64MB): xb @0-32 | P (16 x 2MB segs) @32-64.
    //   Wbb@56, Wcb@58 die after projBC (P segs 12-15 overwrite them).
    char* ob = (char*)d_out;
    unsigned short* xb  = (unsigned short*)ob;
    unsigned short* Pp  = (unsigned short*)(ob + 32 * MB);
    unsigned short* Wbb = (unsigned short*)(ob + 56 * MB);   // Wbb|Wcb contiguous [2048][1024]
    unsigned short* Wcb = (unsigned short*)(ob + 58 * MB);

    dim3 blk256(256, 1, 1);
    dim3 blk512(512, 1, 1);
    dim3 gBC(2048 / 256, S_ / 256, B_);        // (8,16,4) = 512
    dim3 gE(D_ / 256, D_ / 256, B_ * 4);       // (4,4,16) = 256, split-K=4
    dim3 gS(D_ / 256, S_ / 256, B_);           // (4,16,4) = 256
    dim3 gF(D_ / BN, D_ / BM, B_);             // (8,8,4)

    const int n8x = (B_ * S_ * D_) / 8;
    const int n8w = (D_ * D_) / 8;
    const int n8e = (B_ * D_ * D_) / 8;

    // 0) convert x, Wb, Wc (one launch)
    conv_all<<<2048, blk256, 0, stream>>>(x, Wb, Wc, xb, Wbb, Wcb, n8x, n8w);
    // 1) fused projections: BC[b][n][s] = relu(xb [Wb;Wc]^T)^T, n in [0,2048)
    gemm256<false, true,  true ><<<gBC, blk512, 0, stream>>>(xb, Wbb, BC, S_, 2048, D_, D_, 1, SD, 0, 2 * SD);
    // 2) E partials: P[b*4+seg] = sum_{s in seg} Bm[s,e] C[s,e']
    gemm256<false, false, false><<<gE, blk512, 0, stream>>>(BC, BC + SD, Pp, D_, D_, S_, S_ / 4, 4, 2 * SD, 2 * SD, DD2);
    // 2b) Enorm = sum_seg P (contiguous, ws@0) + convert Wd, Wa (one launch)
    reduce_convw<<<1024, blk256, 0, stream>>>(Pp, Enorm, Wd, Wa, Wdb, Wab, n8e, n8w);
    // 3) Ft[b][dout][e] = (Enorm[b] @ Wd^T)^T  (contiguous Enorm, sA = DD2)
    gemm_nt<false, true,  false><<<gF, blk256, 0, stream>>>(Enorm, Wdb, Ft, D_, D_, D_, D_, 1, DD2, 0, DD2);
    // 4) A[b][s][e] = relu(xb Wa^T) -> Ao (ws@0, Enorm dead)
    gemm256<false, false, true ><<<gS, blk512, 0, stream>>>(xb, Wab, Ao, S_, D_, D_, D_, 1, SD, 0, SD);
    // 5) out = relu(A @ Ft-rows) f32 -> d_out (reads only ws; overwrites d_out)
    gemm256<true,  false, true ><<<gS, blk512, 0, stream>>>(Ao, Ft, (float*)d_out, S_, D_, D_, D_, 1, SD, DD2, SD);
}